// Round 8
// baseline (254.721 us; speedup 1.0000x reference)
//
#include <hip/hip_runtime.h>
#include <hip/hip_cooperative_groups.h>

namespace cg = cooperative_groups;

#define NBATCH 16
#define NANCH  3
#define NGRID  64
#define NT     60
#define NPB    (NANCH*NGRID*NGRID)   // 12288 cells per batch
#define NCELL  (NBATCH*NPB)          // 196608 total cells
#define NLBL   (NBATCH*NT)           // 960 labels
#define NBPB   (NPB/256)             // 48 cell-blocks per batch
#define NBLK   (NBATCH*NBPB + 1)     // 768 cell blocks + 1 build_target block
#define FEPS   1e-16f

// acc slots (global doubles); bacc = per-batch [16][8] doubles
enum { A_XY=0, A_WH, A_IG, A_PG, A_GG, A_HM, A_NACC };
// zero region: obj_bits (6144 w) + gtbest (1920 w) + acc (32 w) + bacc (256 w)
#define ZWORDS ((NCELL/32) + (NLBL*2) + 32 + 256)

__device__ __forceinline__ float frcp(float x) { return __builtin_amdgcn_rcpf(x); }
__device__ __forceinline__ float sigm(float x) { return frcp(1.0f + __expf(-x)); }

__device__ __forceinline__ float waveSum(float v) {
#pragma unroll
    for (int o = 32; o > 0; o >>= 1) v += __shfl_down(v, o, 64);
    return v;
}

__device__ __forceinline__ unsigned int ford(float f) {
    unsigned int u = __float_as_uint(f);
    return (u & 0x80000000u) ? ~u : (u | 0x80000000u);
}
__device__ __forceinline__ float ford_inv(unsigned int u) {
    unsigned int v = (u & 0x80000000u) ? (u & 0x7fffffffu) : ~u;
    return __uint_as_float(v);
}

__device__ __forceinline__ void gou_pair(float px1, float py1, float px2, float py2, float pa,
                                         float gx1, float gy1, float gx2, float gy2, float ga,
                                         float& iou, float& gou) {
    float iw = fmaxf(fminf(px2, gx2) - fmaxf(px1, gx1), 0.f);
    float ih = fmaxf(fminf(py2, gy2) - fmaxf(py1, gy1), 0.f);
    float inter = iw * ih;
    float un = pa + ga - inter;
    iou = inter * frcp(un + FEPS);
    float cw = fmaxf(px2, gx2) - fminf(px1, gx1);
    float ch = fmaxf(py2, gy2) - fminf(py1, gy1);
    float ca = cw * ch;
    gou = iou - (ca - un) * frcp(ca + FEPS);
}

// ===========================================================================
// Fused cooperative kernel. 769 blocks x 256 threads, 4 blocks/CU.
// P0 zero -> sync -> P1 decode/pd/gt (+build_target on blk 768) -> sync ->
// P2 distributed per-batch sums (pd results stay in REGISTERS across sync)
// -> sync -> P3 finalize.
// ===========================================================================
__global__ __launch_bounds__(256, 4)
void kFused(const float* __restrict__ out, const float* __restrict__ labels,
            const float4* __restrict__ io4, const float4* __restrict__ hm4,
            unsigned int* __restrict__ obj_bits,
            unsigned long long* __restrict__ gtbest,
            double* __restrict__ acc, double* __restrict__ bacc,
            unsigned int* __restrict__ zbase, float* __restrict__ outp) {
    cg::grid_group grid = cg::this_grid();
    int blk = blockIdx.x, thr = threadIdx.x;
    int wave = thr >> 6, lane = thr & 63;

    // ---- P0: zero control state (grid-strided)
    for (int i = blk * 256 + thr; i < ZWORDS; i += NBLK * 256) zbase[i] = 0u;
    grid.sync();

    __shared__ float4 G4[NT];
    __shared__ float  GA[NT];
    __shared__ float4 Bxy[256];
    __shared__ float  Bpa[256];
    __shared__ int    keys[NLBL];
    __shared__ unsigned long long Wn[NT];
    __shared__ float  red[8][4];

    // registers carried P1 -> P2
    float px1 = 0, py1 = 0, px2 = 0, py2 = 0, pa = 0, cf = 0, pdg = 0, pdi = 0;
    int b = 0, n = 0, idx = 0;

    // ---- P1
    if (blk < NBLK - 1) {
        b = blk / NBPB;
        int s = blk - b * NBPB;
        n = s * 256 + thr;
        idx = b * NPB + n;

        if (thr < NT) {
            const float* lp = labels + (b * NT + thr) * 5;
            float gx = lp[1], gy = lp[2], gw = lp[3], gh = lp[4];
            G4[thr] = make_float4(gx - gw * 0.5f, gy - gh * 0.5f,
                                  gx + gw * 0.5f, gy + gh * 0.5f);
            GA[thr] = gw * gh;
        }

        int a = n >> 12, gj = (n >> 6) & 63, gi = n & 63;
        int base = ((b * NANCH * 5 + a * 5) * NGRID + gj) * NGRID + gi;
        float xs = sigm(out[base]);
        float ys = sigm(out[base + NGRID * NGRID]);
        float ws = sigm(out[base + 2 * NGRID * NGRID]);
        float hs = sigm(out[base + 3 * NGRID * NGRID]);
        cf = sigm(out[base + 4 * NGRID * NGRID]);

        float bx = (xs + (float)gi) * (1.0f / NGRID);
        float by = (ys + (float)gj) * (1.0f / NGRID);
        px1 = bx - ws * 0.5f; px2 = bx + ws * 0.5f;
        py1 = by - hs * 0.5f; py2 = by + hs * 0.5f;
        pa = ws * hs;

        Bxy[thr] = make_float4(px1, py1, px2, py2);
        Bpa[thr] = pa;
        __syncthreads();

        // pd-side: this cell vs 60 GTs (first-t tie-break); result stays in regs
        float best = -1e30f, biou = 0.0f;
        for (int t = 0; t < NT; ++t) {
            float4 g = G4[t];
            float iou, gou;
            gou_pair(px1, py1, px2, py2, pa, g.x, g.y, g.z, g.w, GA[t], iou, gou);
            if (gou > best) { best = gou; biou = iou; }
        }
        pdg = best; pdi = biou;

        // gt-side: lane = GT t; wave scans its 64 cells via LDS broadcast
        {
            int t = (lane < NT) ? lane : 0;
            float4 g = G4[t];
            float ga = GA[t];
            int cbase = wave * 64;
            int nbase = s * 256 + cbase;
            unsigned long long bp = 0ull;
#pragma unroll 4
            for (int i = 0; i < 64; ++i) {
                float4 p = Bxy[cbase + i];
                float cpa = Bpa[cbase + i];
                float iou, gou;
                gou_pair(p.x, p.y, p.z, p.w, cpa, g.x, g.y, g.z, g.w, ga, iou, gou);
                unsigned long long pk = ((unsigned long long)ford(gou) << 32)
                                      | (0xFFFFFFFFu - (unsigned int)(nbase + i));
                if (pk > bp) bp = pk;    // ascending n + strict > = first-index ties
            }
            if (lane < NT) atomicMax(&gtbest[b * NT + lane], bp);
        }

        // heatmap MSE + pg
        float4 ha = io4[idx], hb = hm4[idx];
        float d0 = ha.x - hb.x, d1 = ha.y - hb.y, d2 = ha.z - hb.z, d3 = ha.w - hb.w;
        float hsum = d0 * d0 + d1 * d1 + d2 * d2 + d3 * d3;
        float v = waveSum(cf * cf);
        float h = waveSum(hsum);
        if (lane == 0) { red[0][wave] = v; red[1][wave] = h; }
        __syncthreads();
        if (thr == 0) {
            atomicAdd(&acc[A_PG], (double)(red[0][0] + red[0][1] + red[0][2] + red[0][3]));
            atomicAdd(&acc[A_HM], (double)(red[1][0] + red[1][1] + red[1][2] + red[1][3]));
        }
    } else {
        // -------- build_target block: 256 threads x 4 labels, hidden under P1
#pragma unroll
        for (int c = 0; c < 4; ++c) {
            int j = c * 256 + thr;
            if (j < NLBL) {
                const float* lp = labels + j * 5;
                int lb = (int)lp[0];
                float bxf = lp[1] * (float)NGRID;
                float byf = lp[2] * (float)NGRID;
                int gi = (int)bxf, gj = (int)byf;
                keys[j] = (lb * NGRID + gj) * NGRID + gi;
            }
        }
        __syncthreads();

        float sxy = 0.f, swh = 0.f, sig_ = 0.f, scnt = 0.f;
#pragma unroll
        for (int c = 0; c < 4; ++c) {
            int j = c * 256 + thr;
            if (j < NLBL) {
                int key = keys[j];
                int occ = 0;
                for (int i = 0; i < j; ++i)
                    if (keys[i] == key) occ++;
                if (occ < NANCH) {
                    const float* lp = labels + j * 5;
                    int lb = (int)lp[0];
                    float bxf = lp[1] * (float)NGRID;
                    float byf = lp[2] * (float)NGRID;
                    float lw_ = lp[3], lh_ = lp[4];
                    int gi = (int)bxf, gj = (int)byf;
                    int a = occ;
                    int cell = ((lb * NANCH + a) * NGRID + gj) * NGRID + gi;
                    atomicOr(&obj_bits[cell >> 5], 1u << (cell & 31));
                    int base = ((lb * NANCH * 5 + a * 5) * NGRID + gj) * NGRID + gi;
                    float xs = sigm(out[base]);
                    float ys = sigm(out[base + NGRID * NGRID]);
                    float ws = sigm(out[base + 2 * NGRID * NGRID]);
                    float hs = sigm(out[base + 3 * NGRID * NGRID]);
                    float cfl = sigm(out[base + 4 * NGRID * NGRID]);
                    float tx = bxf - floorf(bxf);
                    float ty = byf - floorf(byf);
                    float dx = xs - tx, dy = ys - ty;
                    sxy += dx * dx + dy * dy;
                    float dw = __logf(ws) - __logf(lw_);
                    float dh = __logf(hs) - __logf(lh_);
                    swh += dw * dw + dh * dh;
                    sig_ += cfl;
                    scnt += 1.f;
                }
            }
        }
        float vals[4] = { sxy, swh, sig_, scnt };
#pragma unroll
        for (int k = 0; k < 4; ++k) {
            float vv = waveSum(vals[k]);
            if (lane == 0) red[k][wave] = vv;
        }
        __syncthreads();
        if (thr == 0) {
            atomicAdd(&acc[A_XY], (double)(red[0][0] + red[0][1] + red[0][2] + red[0][3]));
            atomicAdd(&acc[A_WH], (double)(red[1][0] + red[1][1] + red[1][2] + red[1][3]));
            atomicAdd(&acc[A_IG], (double)(red[2][0] + red[2][1] + red[2][2] + red[2][3]));
            atomicAdd(&acc[A_GG], (double)(red[3][0] + red[3][1] + red[3][2] + red[3][3]));
        }
    }
    grid.sync();

    // ---- P2: distributed per-batch sums (pd results + box still in registers)
    if (blk < NBLK - 1) {
        if (thr < NT) Wn[thr] = gtbest[b * NT + thr];
        __syncthreads();

        bool m_ = false;
        float sgou = 0.f, siou = 0.f;
        for (int t = 0; t < NT; ++t) {
            unsigned long long pk = Wn[t];
            int wn = (int)(0xFFFFFFFFu - (unsigned int)(pk & 0xFFFFFFFFu));
            if (wn == n) {            // this thread's cell is GT t's winner
                m_ = true;
                float g1 = ford_inv((unsigned int)(pk >> 32));
                float4 g = G4[t];
                float iou, gd;
                gou_pair(px1, py1, px2, py2, pa, g.x, g.y, g.z, g.w, GA[t], iou, gd);
                sgou += 1.f - g1;
                siou += 1.f - iou;
            }
        }
        bool mk = (pdi >= 0.5f);
        bool ob = (obj_bits[idx >> 5] >> (idx & 31)) & 1u;
        float m2 = (mk || m_) ? 1.f : 0.f;
        float ign = (!mk || m_) ? 1.f : 0.f;
        float tc = (ob || m_) ? 1.f : 0.f;
        float vals8[8] = { m2, (1.f - pdg) * m2, (1.f - pdi) * m2,
                           cf * tc * ign, cf * cf * ign, tc * ign, sgou, siou };
#pragma unroll
        for (int k = 0; k < 8; ++k) {
            float vv = waveSum(vals8[k]);
            if (lane == 0) red[k][wave] = vv;
        }
        __syncthreads();
        if (thr == 0) {
#pragma unroll
            for (int k = 0; k < 8; ++k)
                atomicAdd(&bacc[b * 8 + k],
                          (double)(red[k][0] + red[k][1] + red[k][2] + red[k][3]));
        }
    }
    grid.sync();

    // ---- P3: finalize
    if (blk == 0 && thr == 0) {
        double cnt = acc[A_GG];
        double lxy = acc[A_XY] / cnt;
        double lwh = acc[A_WH] / cnt;
        double sgouT = 0, siouT = 0, gou2 = 0, iou2 = 0, confbT = 0;
        for (int bb = 0; bb < NBATCH; ++bb) {
            double c2 = bacc[bb * 8 + 0];
            gou2 += bacc[bb * 8 + 1] / c2;
            iou2 += bacc[bb * 8 + 2] / c2;
            confbT += 1.0 - (2.0 * bacc[bb * 8 + 3] + 1.0)
                          / (bacc[bb * 8 + 4] + bacc[bb * 8 + 5] + 1.0);
            sgouT += bacc[bb * 8 + 6];
            siouT += bacc[bb * 8 + 7];
        }
        double lgou = sgouT / (double)NLBL + gou2 / (double)NBATCH;
        double liou = siouT / (double)NLBL + iou2 / (double)NBATCH;
        double dice = (2.0 * acc[A_IG] + 1.0) / (acc[A_PG] + acc[A_GG] + 1.0);
        if (dice != dice) dice = 1.0;
        double lconf = 1.0 - dice + confbT / (double)NBATCH;
        double total = lxy + lwh + lconf + lgou;
        double hmv = acc[A_HM] / (double)(4 * NCELL);
        outp[0] = (float)lxy;
        outp[1] = (float)lwh;
        outp[2] = (float)lconf;
        outp[3] = (float)liou;
        outp[4] = (float)lgou;
        outp[5] = (float)total;
        outp[6] = (float)hmv;
    }
}

// ===========================================================================
// Fallback path (round-7 kernels, verbatim) in case cooperative launch is
// rejected by the runtime/graph-capture. Proven passing at absmax 0.0.
// ===========================================================================
enum { B_XY=0, B_WH, B_IG, B_PG, B_GG, B_HM, B_GOU2, B_IOU2, B_CONFB, B_GTGOU, B_GTIOU, B_NACC };

__global__ __launch_bounds__(1024)
void kA_fb(const float* __restrict__ labels, const float* __restrict__ out,
           unsigned int* __restrict__ obj_bits, unsigned long long* __restrict__ gtbest,
           double* __restrict__ acc) {
    for (int i = threadIdx.x; i < NCELL / 32; i += 1024) obj_bits[i] = 0u;
    for (int i = threadIdx.x; i < NLBL; i += 1024) gtbest[i] = 0ull;
    if (threadIdx.x < B_NACC) acc[threadIdx.x] = 0.0;

    __shared__ int keys[NLBL];
    __shared__ float red[16];
    int j = threadIdx.x;
    int b = 0, gi = 0, gj = 0, key = 0;
    float bx = 0.f, by = 0.f, lw_ = 0.f, lh_ = 0.f;
    if (j < NLBL) {
        const float* lp = labels + j * 5;
        b = (int)lp[0];
        bx = lp[1] * (float)NGRID;
        by = lp[2] * (float)NGRID;
        lw_ = lp[3]; lh_ = lp[4];
        gi = (int)bx; gj = (int)by;
        key = (b * NGRID + gj) * NGRID + gi;
        keys[j] = key;
    }
    __syncthreads();
    float sxy = 0.f, swh = 0.f, sig_ = 0.f, scnt = 0.f;
    if (j < NLBL) {
        int occ = 0;
        for (int i = 0; i < j; ++i)
            if (keys[i] == key) occ++;
        if (occ < NANCH) {
            int a = occ;
            int cell = ((b * NANCH + a) * NGRID + gj) * NGRID + gi;
            atomicOr(&obj_bits[cell >> 5], 1u << (cell & 31));
            int base = ((b * NANCH * 5 + a * 5) * NGRID + gj) * NGRID + gi;
            float xs = sigm(out[base]);
            float ys = sigm(out[base + NGRID * NGRID]);
            float ws = sigm(out[base + 2 * NGRID * NGRID]);
            float hs = sigm(out[base + 3 * NGRID * NGRID]);
            float cf = sigm(out[base + 4 * NGRID * NGRID]);
            float tx = bx - floorf(bx);
            float ty = by - floorf(by);
            float dx = xs - tx, dy = ys - ty;
            sxy = dx * dx + dy * dy;
            float dw = __logf(ws) - __logf(lw_);
            float dh = __logf(hs) - __logf(lh_);
            swh = dw * dw + dh * dh;
            sig_ = cf; scnt = 1.f;
        }
    }
    float vals[4] = { sxy, swh, sig_, scnt };
    int wave = threadIdx.x >> 6, lane = threadIdx.x & 63;
#pragma unroll
    for (int k = 0; k < 4; ++k) {
        float v = waveSum(vals[k]);
        if (lane == 0) red[wave] = v;
        __syncthreads();
        if (threadIdx.x == 0) {
            float r = 0.f;
            for (int w = 0; w < 16; ++w) r += red[w];
            vals[k] = r;
        }
        __syncthreads();
    }
    if (threadIdx.x == 0) {
        acc[B_XY] = (double)vals[0];
        acc[B_WH] = (double)vals[1];
        acc[B_IG] = (double)vals[2];
        acc[B_GG] = (double)vals[3];
    }
}

__global__ __launch_bounds__(256)
void kB_fb(const float* __restrict__ out, const float* __restrict__ labels,
           const float4* __restrict__ io4, const float4* __restrict__ hm4,
           float4* __restrict__ Pxy, float2* __restrict__ Pac,
           float* __restrict__ pd_gou, float* __restrict__ pd_iou,
           unsigned long long* __restrict__ gtbest, double* __restrict__ acc) {
    int idx = blockIdx.x * 256 + threadIdx.x;
    int b = blockIdx.x / NBPB;
    int s = blockIdx.x - b * NBPB;
    int n = s * 256 + threadIdx.x;
    int wave = threadIdx.x >> 6, lane = threadIdx.x & 63;
    __shared__ float4 G4[NT];
    __shared__ float  GA[NT];
    __shared__ float4 Bxy[256];
    __shared__ float  Bpa[256];
    __shared__ float red[4], red2[4];
    if (threadIdx.x < NT) {
        const float* lp = labels + (b * NT + threadIdx.x) * 5;
        float gx = lp[1], gy = lp[2], gw = lp[3], gh = lp[4];
        G4[threadIdx.x] = make_float4(gx - gw * 0.5f, gy - gh * 0.5f,
                                      gx + gw * 0.5f, gy + gh * 0.5f);
        GA[threadIdx.x] = gw * gh;
    }
    int a = n >> 12, gj = (n >> 6) & 63, gi = n & 63;
    int base = ((b * NANCH * 5 + a * 5) * NGRID + gj) * NGRID + gi;
    float xs = sigm(out[base]);
    float ys = sigm(out[base + NGRID * NGRID]);
    float ws = sigm(out[base + 2 * NGRID * NGRID]);
    float hs = sigm(out[base + 3 * NGRID * NGRID]);
    float cf = sigm(out[base + 4 * NGRID * NGRID]);
    float bx = (xs + (float)gi) * (1.0f / NGRID);
    float by = (ys + (float)gj) * (1.0f / NGRID);
    float px1 = bx - ws * 0.5f, px2 = bx + ws * 0.5f;
    float py1 = by - hs * 0.5f, py2 = by + hs * 0.5f;
    float pa = ws * hs;
    Pxy[idx] = make_float4(px1, py1, px2, py2);
    Pac[idx] = make_float2(pa, cf);
    Bxy[threadIdx.x] = make_float4(px1, py1, px2, py2);
    Bpa[threadIdx.x] = pa;
    __syncthreads();
    float best = -1e30f, biou = 0.0f;
    for (int t = 0; t < NT; ++t) {
        float4 g = G4[t];
        float iou, gou;
        gou_pair(px1, py1, px2, py2, pa, g.x, g.y, g.z, g.w, GA[t], iou, gou);
        if (gou > best) { best = gou; biou = iou; }
    }
    pd_gou[idx] = best;
    pd_iou[idx] = biou;
    {
        int t = (lane < NT) ? lane : 0;
        float4 g = G4[t];
        float ga = GA[t];
        int cbase = wave * 64;
        int nbase = s * 256 + cbase;
        unsigned long long bestp = 0ull;
#pragma unroll 4
        for (int i = 0; i < 64; ++i) {
            float4 p = Bxy[cbase + i];
            float cpa = Bpa[cbase + i];
            float iou, gou;
            gou_pair(p.x, p.y, p.z, p.w, cpa, g.x, g.y, g.z, g.w, ga, iou, gou);
            unsigned long long pk = ((unsigned long long)ford(gou) << 32)
                                  | (0xFFFFFFFFu - (unsigned int)(nbase + i));
            if (pk > bestp) bestp = pk;
        }
        if (lane < NT) atomicMax(&gtbest[b * NT + lane], bestp);
    }
    float4 ha = io4[idx], hb = hm4[idx];
    float d0 = ha.x - hb.x, d1 = ha.y - hb.y, d2 = ha.z - hb.z, d3 = ha.w - hb.w;
    float hsum = d0 * d0 + d1 * d1 + d2 * d2 + d3 * d3;
    float v = waveSum(cf * cf);
    float h = waveSum(hsum);
    if (lane == 0) { red[wave] = v; red2[wave] = h; }
    __syncthreads();
    if (threadIdx.x == 0) {
        atomicAdd(&acc[B_PG], (double)(red[0] + red[1] + red[2] + red[3]));
        atomicAdd(&acc[B_HM], (double)(red2[0] + red2[1] + red2[2] + red2[3]));
    }
}

__global__ __launch_bounds__(256)
void kD_fb(const float4* __restrict__ Pxy, const float2* __restrict__ Pac,
           const float* __restrict__ pd_gou, const float* __restrict__ pd_iou,
           const unsigned int* __restrict__ obj_bits,
           const unsigned long long* __restrict__ gtbest,
           const float* __restrict__ labels, double* __restrict__ acc) {
    int b = blockIdx.x;
    __shared__ unsigned int mbits[NPB / 32];
    for (int w = threadIdx.x; w < NPB / 32; w += 256) mbits[w] = 0u;
    __syncthreads();
    float sgou = 0.f, siou = 0.f;
    if (threadIdx.x < NT) {
        int t = threadIdx.x;
        unsigned long long pk = gtbest[b * NT + t];
        float gou = ford_inv((unsigned int)(pk >> 32));
        int n = (int)(0xFFFFFFFFu - (unsigned int)(pk & 0xFFFFFFFFu));
        atomicOr(&mbits[n >> 5], 1u << (n & 31));
        int idx = b * NPB + n;
        float4 pbx = Pxy[idx];
        float pa = Pac[idx].x;
        const float* lp = labels + (b * NT + t) * 5;
        float gx = lp[1], gy = lp[2], gw = lp[3], gh = lp[4];
        float iou, gdummy;
        gou_pair(pbx.x, pbx.y, pbx.z, pbx.w, pa,
                 gx - gw * 0.5f, gy - gh * 0.5f, gx + gw * 0.5f, gy + gh * 0.5f,
                 gw * gh, iou, gdummy);
        sgou = 1.f - gou;
        siou = 1.f - iou;
    }
    if ((threadIdx.x >> 6) == 0) {
        float a1 = waveSum(sgou);
        float a2 = waveSum(siou);
        if (threadIdx.x == 0) {
            atomicAdd(&acc[B_GTGOU], (double)a1);
            atomicAdd(&acc[B_GTIOU], (double)a2);
        }
    }
    __syncthreads();
    float c2 = 0.f, sg = 0.f, si = 0.f, sin_ = 0.f, spa = 0.f, sga = 0.f;
    for (int n = threadIdx.x; n < NPB; n += 256) {
        int idx = b * NPB + n;
        float pio = pd_iou[idx];
        float pgo = pd_gou[idx];
        float cf = Pac[idx].y;
        bool mk = (pio >= 0.5f);
        bool m_ = (mbits[n >> 5] >> (n & 31)) & 1u;
        bool ob = (obj_bits[idx >> 5] >> (idx & 31)) & 1u;
        float m2 = (mk || m_) ? 1.f : 0.f;
        float ign = (!mk || m_) ? 1.f : 0.f;
        float tc = (ob || m_) ? 1.f : 0.f;
        c2 += m2;
        sg += (1.f - pgo) * m2;
        si += (1.f - pio) * m2;
        sin_ += cf * tc * ign;
        spa += cf * cf * ign;
        sga += tc * ign;
    }
    float vals[6] = { c2, sg, si, sin_, spa, sga };
    __shared__ float red[4];
    int wave = threadIdx.x >> 6, lane = threadIdx.x & 63;
#pragma unroll
    for (int k = 0; k < 6; ++k) {
        float v = waveSum(vals[k]);
        if (lane == 0) red[wave] = v;
        __syncthreads();
        if (threadIdx.x == 0) vals[k] = red[0] + red[1] + red[2] + red[3];
        __syncthreads();
    }
    if (threadIdx.x == 0) {
        atomicAdd(&acc[B_GOU2], (double)(vals[1] / vals[0]));
        atomicAdd(&acc[B_IOU2], (double)(vals[2] / vals[0]));
        float confb = 1.0f - (2.0f * vals[3] + 1.0f) / (vals[4] + vals[5] + 1.0f);
        atomicAdd(&acc[B_CONFB], (double)confb);
    }
}

__global__ void kF_fb(const double* __restrict__ acc, float* __restrict__ outp) {
    if (threadIdx.x == 0 && blockIdx.x == 0) {
        double cnt = acc[B_GG];
        double lxy = acc[B_XY] / cnt;
        double lwh = acc[B_WH] / cnt;
        double lgou = acc[B_GTGOU] / (double)NLBL + acc[B_GOU2] / (double)NBATCH;
        double liou = acc[B_GTIOU] / (double)NLBL + acc[B_IOU2] / (double)NBATCH;
        double dice = (2.0 * acc[B_IG] + 1.0) / (acc[B_PG] + acc[B_GG] + 1.0);
        if (dice != dice) dice = 1.0;
        double lconf = 1.0 - dice + acc[B_CONFB] / (double)NBATCH;
        double total = lxy + lwh + lconf + lgou;
        double hmv = acc[B_HM] / (double)(4 * NCELL);
        outp[0] = (float)lxy; outp[1] = (float)lwh; outp[2] = (float)lconf;
        outp[3] = (float)liou; outp[4] = (float)lgou; outp[5] = (float)total;
        outp[6] = (float)hmv;
    }
}

// ---------------------------------------------------------------------------
extern "C" void kernel_launch(void* const* d_in, const int* in_sizes, int n_in,
                              void* d_out, int out_size, void* d_ws, size_t ws_size,
                              hipStream_t stream) {
    const float* out_p    = (const float*)d_in[0];
    const float* labels   = (const float*)d_in[1];
    const float4* io4     = (const float4*)d_in[2];
    const float4* hm4     = (const float4*)d_in[3];
    float* o = (float*)d_out;

    char* ws = (char*)d_ws;
    // fused layout: obj_bits | gtbest | acc | bacc (contiguous zero region)
    unsigned int* obj_bits = (unsigned int*)(ws);                          // 24576 B
    unsigned long long* gtbest = (unsigned long long*)(ws + 24576);        // 7680 B
    double* acc  = (double*)(ws + 32256);                                  // 128 B
    double* bacc = (double*)(ws + 32384);                                  // 1024 B
    unsigned int* zbase = (unsigned int*)ws;

    void* args[] = { (void*)&out_p, (void*)&labels, (void*)&io4, (void*)&hm4,
                     (void*)&obj_bits, (void*)&gtbest, (void*)&acc, (void*)&bacc,
                     (void*)&zbase, (void*)&o };
    hipError_t e = hipLaunchCooperativeKernel((void*)kFused, dim3(NBLK), dim3(256),
                                              args, 0, stream);
    if (e != hipSuccess) {
        (void)hipGetLastError();   // clear error state, take the classic path
        // fallback layout (independent region past the fused header)
        char* fb = ws + 65536;
        unsigned int* f_obj = (unsigned int*)(fb);
        double* f_acc = (double*)(fb + NCELL / 8);
        unsigned long long* f_gt = (unsigned long long*)(fb + NCELL / 8 + 16 * sizeof(double));
        size_t hdr = NCELL / 8 + 16 * sizeof(double) + (size_t)NLBL * 8;
        float4* Pxy    = (float4*)(fb + hdr);
        float*  pd_gou = (float*)(fb + hdr + (size_t)NCELL * 16);
        float*  pd_iou = (float*)(fb + hdr + (size_t)NCELL * 20);
        float2* Pac    = (float2*)(fb + hdr + (size_t)NCELL * 24);
        hipLaunchKernelGGL(kA_fb, dim3(1), dim3(1024), 0, stream,
                           labels, out_p, f_obj, f_gt, f_acc);
        hipLaunchKernelGGL(kB_fb, dim3(NCELL / 256), dim3(256), 0, stream, out_p, labels,
                           io4, hm4, Pxy, Pac, pd_gou, pd_iou, f_gt, f_acc);
        hipLaunchKernelGGL(kD_fb, dim3(NBATCH), dim3(256), 0, stream, Pxy, Pac, pd_gou, pd_iou,
                           f_obj, f_gt, labels, f_acc);
        hipLaunchKernelGGL(kF_fb, dim3(1), dim3(64), 0, stream, f_acc, o);
    }
}

// Round 9
// 57.332 us; speedup vs baseline: 4.4429x; 4.4429x over previous
//
#include <hip/hip_runtime.h>

#define NBATCH 16
#define NANCH  3
#define NGRID  64
#define NT     60
#define NPB    (NANCH*NGRID*NGRID)   // 12288 cells per batch
#define NCELL  (NBATCH*NPB)          // 196608 total cells
#define NLBL   (NBATCH*NT)           // 960 labels
#define NBPB   (NPB/256)             // 48 cell-blocks per batch
#define NBLKB  (NBATCH*NBPB)         // 768 kB blocks
#define FEPS   1e-16f

__device__ __forceinline__ float frcp(float x) { return __builtin_amdgcn_rcpf(x); }
__device__ __forceinline__ float sigm(float x) { return frcp(1.0f + __expf(-x)); }

__device__ __forceinline__ float waveSum(float v) {
#pragma unroll
    for (int o = 32; o > 0; o >>= 1) v += __shfl_down(v, o, 64);
    return v;
}
__device__ __forceinline__ double waveSumD(double v) {
#pragma unroll
    for (int o = 32; o > 0; o >>= 1) v += __shfl_down(v, o, 64);
    return v;
}

__device__ __forceinline__ unsigned int ford(float f) {
    unsigned int u = __float_as_uint(f);
    return (u & 0x80000000u) ? ~u : (u | 0x80000000u);
}
__device__ __forceinline__ float ford_inv(unsigned int u) {
    unsigned int v = (u & 0x80000000u) ? (u & 0x7fffffffu) : ~u;
    return __uint_as_float(v);
}

__device__ __forceinline__ void gou_pair(float px1, float py1, float px2, float py2, float pa,
                                         float gx1, float gy1, float gx2, float gy2, float ga,
                                         float& iou, float& gou) {
    float iw = fmaxf(fminf(px2, gx2) - fmaxf(px1, gx1), 0.f);
    float ih = fmaxf(fminf(py2, gy2) - fmaxf(py1, gy1), 0.f);
    float inter = iw * ih;
    float un = pa + ga - inter;
    iou = inter * frcp(un + FEPS);
    float cw = fmaxf(px2, gx2) - fminf(px1, gx1);
    float ch = fmaxf(py2, gy2) - fminf(py1, gy1);
    float ca = cw * ch;
    gou = iou - (ca - un) * frcp(ca + FEPS);
}

// ---------------------------------------------------------------------------
// Kernel B: 768 blocks. Per-cell decode, pd-side max over 60 GTs, gt-side
// lane-per-GT block winner (LDS combine, plain store — NO global atomics,
// NO zero-init needed: gtpart/gtiou/partials fully overwritten each call).
// Also recomputes the block-winner's iou from LDS boxes (so kD needs no
// boxes), per-block pg/hm partials, and re-zeroes the kD ticket.
// ---------------------------------------------------------------------------
__global__ __launch_bounds__(256)
void kB(const float* __restrict__ out, const float* __restrict__ labels,
        const float4* __restrict__ io4, const float4* __restrict__ hm4,
        unsigned long long* __restrict__ gtpart, float* __restrict__ gtiou,
        float* __restrict__ pd_gou, float* __restrict__ pd_iou,
        float* __restrict__ conf_a,
        double* __restrict__ pgpart, double* __restrict__ hmpart,
        unsigned int* __restrict__ ticket) {
    int blk = blockIdx.x, thr = threadIdx.x;
    if (blk == 0 && thr == 0) *ticket = 0u;    // stream order: visible to kD

    int b = blk / NBPB;
    int s = blk - b * NBPB;
    int n = s * 256 + thr;                     // cell within batch
    int idx = b * NPB + n;
    int wave = thr >> 6, lane = thr & 63;

    __shared__ float4 G4[NT];
    __shared__ float  GA[NT];
    __shared__ float4 Bxy[256];
    __shared__ float  Bpa[256];
    __shared__ unsigned long long W[4][NT];
    __shared__ float red[2][4];

    if (thr < NT) {
        const float* lp = labels + (b * NT + thr) * 5;
        float gx = lp[1], gy = lp[2], gw = lp[3], gh = lp[4];
        G4[thr] = make_float4(gx - gw * 0.5f, gy - gh * 0.5f,
                              gx + gw * 0.5f, gy + gh * 0.5f);
        GA[thr] = gw * gh;
    }

    int a = n >> 12, gj = (n >> 6) & 63, gi = n & 63;
    int base = ((b * NANCH * 5 + a * 5) * NGRID + gj) * NGRID + gi;
    float xs = sigm(out[base]);
    float ys = sigm(out[base + NGRID * NGRID]);
    float ws = sigm(out[base + 2 * NGRID * NGRID]);
    float hs = sigm(out[base + 3 * NGRID * NGRID]);
    float cf = sigm(out[base + 4 * NGRID * NGRID]);

    float bx = (xs + (float)gi) * (1.0f / NGRID);
    float by = (ys + (float)gj) * (1.0f / NGRID);
    float px1 = bx - ws * 0.5f, px2 = bx + ws * 0.5f;
    float py1 = by - hs * 0.5f, py2 = by + hs * 0.5f;
    float pa = ws * hs;

    Bxy[thr] = make_float4(px1, py1, px2, py2);
    Bpa[thr] = pa;
    conf_a[idx] = cf;
    __syncthreads();                           // G4/GA + Bxy/Bpa ready

    // --- pd-side: this cell vs 60 GTs (first-t tie-break via strict >)
    float best = -1e30f, biou = 0.0f;
    for (int t = 0; t < NT; ++t) {
        float4 g = G4[t];
        float iou, gou;
        gou_pair(px1, py1, px2, py2, pa, g.x, g.y, g.z, g.w, GA[t], iou, gou);
        if (gou > best) { best = gou; biou = iou; }
    }
    pd_gou[idx] = best;
    pd_iou[idx] = biou;

    // --- gt-side: lane = GT t; wave scans its 64 cells via LDS broadcast.
    {
        int t = (lane < NT) ? lane : 0;
        float4 g = G4[t];
        float ga = GA[t];
        int cbase = wave * 64;
        int nbase = s * 256 + cbase;
        unsigned long long bp = 0ull;          // any real packed value >= 1<<32
#pragma unroll 4
        for (int i = 0; i < 64; ++i) {
            float4 p = Bxy[cbase + i];         // wave-uniform address: broadcast
            float cpa = Bpa[cbase + i];
            float iou, gou;
            gou_pair(p.x, p.y, p.z, p.w, cpa, g.x, g.y, g.z, g.w, ga, iou, gou);
            unsigned long long pk = ((unsigned long long)ford(gou) << 32)
                                  | (0xFFFFFFFFu - (unsigned int)(nbase + i));
            if (pk > bp) bp = pk;              // ascending n + strict > = first-index
        }
        if (lane < NT) W[wave][lane] = bp;
    }
    __syncthreads();

    // combine 4 waves -> block winner per t; recompute its iou from LDS boxes
    if (thr < NT) {
        unsigned long long pk = W[0][thr];
        if (W[1][thr] > pk) pk = W[1][thr];
        if (W[2][thr] > pk) pk = W[2][thr];
        if (W[3][thr] > pk) pk = W[3][thr];
        int wn = (int)(0xFFFFFFFFu - (unsigned int)(pk & 0xFFFFFFFFu));
        int lc = wn - s * 256;                 // winner's local cell index
        float4 p = Bxy[lc];
        float cpa = Bpa[lc];
        float4 g = G4[thr];
        float iou, gd;
        gou_pair(p.x, p.y, p.z, p.w, cpa, g.x, g.y, g.z, g.w, GA[thr], iou, gd);
        gtpart[blk * 64 + thr] = pk;
        gtiou [blk * 64 + thr] = iou;
    }

    // --- per-block pg / heatmap-MSE partials (plain double stores)
    float4 ha = io4[idx], hb = hm4[idx];
    float d0 = ha.x - hb.x, d1 = ha.y - hb.y, d2 = ha.z - hb.z, d3 = ha.w - hb.w;
    float hsum = d0 * d0 + d1 * d1 + d2 * d2 + d3 * d3;
    float v = waveSum(cf * cf);
    float h = waveSum(hsum);
    if (lane == 0) { red[0][wave] = v; red[1][wave] = h; }
    __syncthreads();
    if (thr == 0) {
        pgpart[blk] = (double)(red[0][0] + red[0][1] + red[0][2] + red[0][3]);
        hmpart[blk] = (double)(red[1][0] + red[1][1] + red[1][2] + red[1][3]);
    }
}

// ---------------------------------------------------------------------------
// Kernel D: 16 blocks (one per batch). Phase 1: build_target with a
// BATCH-LOCAL occ scan (keys encode only (gj,gi); cross-batch keys can never
// match since the reference key includes b). Phase 2: reduce 48 block
// winners per GT, set mask bits (LDS), gt gou/iou sums. Phase 3: per-cell
// mask2/ignore/dice sums. Then bacc row + fence + ticket; the 16th block
// finalizes the 7 outputs (coherent atomic reads of all rows).
// ---------------------------------------------------------------------------
__global__ __launch_bounds__(256)
void kD(const float* __restrict__ out, const float* __restrict__ labels,
        const unsigned long long* __restrict__ gtpart, const float* __restrict__ gtiou,
        const float* __restrict__ pd_gou, const float* __restrict__ pd_iou,
        const float* __restrict__ conf_a,
        const double* __restrict__ pgpart, const double* __restrict__ hmpart,
        double* __restrict__ bacc, unsigned int* __restrict__ ticket,
        float* __restrict__ outp) {
    int b = blockIdx.x, thr = threadIdx.x;
    int wave = thr >> 6, lane = thr & 63;

    __shared__ int keys[NT];
    __shared__ unsigned int obits[NPB / 32], mbits[NPB / 32];
    __shared__ float red[8][4];
    __shared__ int finS;
    __shared__ double baccL[256];

    for (int w = thr; w < NPB / 32; w += 256) { obits[w] = 0u; mbits[w] = 0u; }
    if (thr < NT) {
        const float* lp = labels + (b * NT + thr) * 5;
        int gi = (int)(lp[1] * (float)NGRID);
        int gj = (int)(lp[2] * (float)NGRID);
        keys[thr] = (gj << 6) | gi;
    }
    __syncthreads();

    float sxy = 0.f, swh = 0.f, sig_ = 0.f, scnt = 0.f, sgou = 0.f, siou = 0.f;
    if (thr < NT) {
        // ---- phase 1: build_target for label (b, thr)
        int key = keys[thr];
        int occ = 0;
        for (int i = 0; i < thr; ++i)
            if (keys[i] == key) occ++;
        const float* lp = labels + (b * NT + thr) * 5;
        float bxf = lp[1] * (float)NGRID;
        float byf = lp[2] * (float)NGRID;
        float lw_ = lp[3], lh_ = lp[4];
        int gi = (int)bxf, gj = (int)byf;
        if (occ < NANCH) {
            int cell = (occ << 12) | (gj << 6) | gi;       // batch-local n
            atomicOr(&obits[cell >> 5], 1u << (cell & 31));
            int base = ((b * NANCH * 5 + occ * 5) * NGRID + gj) * NGRID + gi;
            float xs = sigm(out[base]);
            float ys = sigm(out[base + NGRID * NGRID]);
            float ws = sigm(out[base + 2 * NGRID * NGRID]);
            float hs = sigm(out[base + 3 * NGRID * NGRID]);
            float cfl = sigm(out[base + 4 * NGRID * NGRID]);
            float tx = bxf - floorf(bxf);
            float ty = byf - floorf(byf);
            float dx = xs - tx, dy = ys - ty;
            sxy = dx * dx + dy * dy;
            float dw = __logf(ws) - __logf(lw_);
            float dh = __logf(hs) - __logf(lh_);
            swh = dw * dw + dh * dh;
            sig_ = cfl;
            scnt = 1.f;
        }
        // ---- phase 2: global gt winner for GT thr (max over 48 block winners)
        unsigned long long bestp = 0ull;
        int sbest = 0;
        for (int ss = 0; ss < NBPB; ++ss) {
            unsigned long long pk = gtpart[(b * NBPB + ss) * 64 + thr];
            if (pk > bestp) { bestp = pk; sbest = ss; }    // pk unique across ss
        }
        float giou = gtiou[(b * NBPB + sbest) * 64 + thr];
        float ggou = ford_inv((unsigned int)(bestp >> 32));
        int wn = (int)(0xFFFFFFFFu - (unsigned int)(bestp & 0xFFFFFFFFu));
        atomicOr(&mbits[wn >> 5], 1u << (wn & 31));
        sgou = 1.f - ggou;
        siou = 1.f - giou;
    }
    // wave-0 reductions of the 6 label-side sums (threads 60-63 hold zeros)
    double labD[6];
    if (wave == 0) {
        labD[0] = (double)waveSum(sxy);
        labD[1] = (double)waveSum(swh);
        labD[2] = (double)waveSum(sig_);
        labD[3] = (double)waveSum(scnt);
        labD[4] = (double)waveSum(sgou);
        labD[5] = (double)waveSum(siou);
    }
    // wave-0: sum this batch's 48 pg/hm partials
    double pgb = 0.0, hmb = 0.0;
    if (wave == 0) {
        double p0 = (lane < NBPB) ? pgpart[b * NBPB + lane] : 0.0;
        double h0 = (lane < NBPB) ? hmpart[b * NBPB + lane] : 0.0;
        pgb = waveSumD(p0);
        hmb = waveSumD(h0);
    }
    __syncthreads();   // obits/mbits complete before phase 3

    // ---- phase 3: per-cell sums
    float c2 = 0.f, sg = 0.f, si = 0.f, sint = 0.f, spa = 0.f, sga = 0.f;
    for (int n = thr; n < NPB; n += 256) {
        int idx = b * NPB + n;
        float pio = pd_iou[idx];
        float pgo = pd_gou[idx];
        float cfv = conf_a[idx];
        bool mk = (pio >= 0.5f);
        bool m_ = (mbits[n >> 5] >> (n & 31)) & 1u;
        bool ob = (obits[n >> 5] >> (n & 31)) & 1u;
        float m2 = (mk || m_) ? 1.f : 0.f;
        float ign = (!mk || m_) ? 1.f : 0.f;
        float tc = (ob || m_) ? 1.f : 0.f;
        c2 += m2;
        sg += (1.f - pgo) * m2;
        si += (1.f - pio) * m2;
        sint += cfv * tc * ign;
        spa += cfv * cfv * ign;
        sga += tc * ign;
    }
    float vals[6] = { c2, sg, si, sint, spa, sga };
#pragma unroll
    for (int k = 0; k < 6; ++k) {
        float vv = waveSum(vals[k]);
        if (lane == 0) red[k][wave] = vv;
    }
    __syncthreads();

    // ---- write bacc row, release-fence, ticket
    if (thr == 0) {
        double* row = &bacc[b * 16];
        row[0]  = (double)(red[0][0] + red[0][1] + red[0][2] + red[0][3]);  // c2
        row[1]  = (double)(red[1][0] + red[1][1] + red[1][2] + red[1][3]);  // sg
        row[2]  = (double)(red[2][0] + red[2][1] + red[2][2] + red[2][3]);  // si
        row[3]  = (double)(red[3][0] + red[3][1] + red[3][2] + red[3][3]);  // sinter
        row[4]  = (double)(red[4][0] + red[4][1] + red[4][2] + red[4][3]);  // spa
        row[5]  = (double)(red[5][0] + red[5][1] + red[5][2] + red[5][3]);  // sga
        row[6]  = labD[4];   // sgou
        row[7]  = labD[5];   // siou
        row[8]  = labD[0];   // sxy
        row[9]  = labD[1];   // swh
        row[10] = labD[2];   // ig
        row[11] = labD[3];   // cnt
        row[12] = pgb;
        row[13] = hmb;
        row[14] = 0.0; row[15] = 0.0;
        __threadfence();
        unsigned int old = atomicAdd(ticket, 1u);
        finS = (old == NBATCH - 1) ? 1 : 0;
    }
    __syncthreads();

    // ---- finalize (the last block only; block-uniform branch)
    if (finS) {
        int bb = thr >> 4, k = thr & 15;
        baccL[thr] = atomicAdd(&bacc[bb * 16 + k], 0.0);   // coherent RMW read
        __syncthreads();
        if (thr == 0) {
            double cnt = 0, sxyT = 0, swhT = 0, igT = 0, pgT = 0, hmT = 0;
            double sgouT = 0, siouT = 0, gou2 = 0, iou2 = 0, confbT = 0;
            for (int q = 0; q < NBATCH; ++q) {
                const double* r = &baccL[q * 16];
                cnt += r[11]; sxyT += r[8]; swhT += r[9]; igT += r[10];
                pgT += r[12]; hmT += r[13];
                sgouT += r[6]; siouT += r[7];
                gou2 += r[1] / r[0];
                iou2 += r[2] / r[0];
                confbT += 1.0 - (2.0 * r[3] + 1.0) / (r[4] + r[5] + 1.0);
            }
            double lxy = sxyT / cnt;
            double lwh = swhT / cnt;
            double lgou = sgouT / (double)NLBL + gou2 / (double)NBATCH;
            double liou = siouT / (double)NLBL + iou2 / (double)NBATCH;
            double dice = (2.0 * igT + 1.0) / (pgT + cnt + 1.0);
            if (dice != dice) dice = 1.0;
            double lconf = 1.0 - dice + confbT / (double)NBATCH;
            double total = lxy + lwh + lconf + lgou;
            double hmv = hmT / (double)(4 * NCELL);
            outp[0] = (float)lxy;
            outp[1] = (float)lwh;
            outp[2] = (float)lconf;
            outp[3] = (float)liou;
            outp[4] = (float)lgou;
            outp[5] = (float)total;
            outp[6] = (float)hmv;
        }
    }
}

// ---------------------------------------------------------------------------
extern "C" void kernel_launch(void* const* d_in, const int* in_sizes, int n_in,
                              void* d_out, int out_size, void* d_ws, size_t ws_size,
                              hipStream_t stream) {
    const float* out_p  = (const float*)d_in[0];
    const float* labels = (const float*)d_in[1];
    const float4* io4   = (const float4*)d_in[2];
    const float4* hm4   = (const float4*)d_in[3];
    float* o = (float*)d_out;

    char* ws = (char*)d_ws;
    unsigned long long* gtpart = (unsigned long long*)(ws);            // 393216 B
    float*  gtiou  = (float*) (ws + 393216);                           // 196608 B
    double* pgpart = (double*)(ws + 589824);                           //   6144 B
    double* hmpart = (double*)(ws + 595968);                           //   6144 B
    double* bacc   = (double*)(ws + 602112);                           //   2048 B
    unsigned int* ticket = (unsigned int*)(ws + 604160);               //     64 B pad
    float* pd_gou  = (float*)(ws + 604224);                            // 786432 B
    float* pd_iou  = (float*)(ws + 1390656);                           // 786432 B
    float* conf_a  = (float*)(ws + 2177088);                           // 786432 B
    // total 2963520 B; everything is fully overwritten each call (kB zeroes
    // the ticket) — no memset, no zero-init ordering hazards.

    hipLaunchKernelGGL(kB, dim3(NBLKB), dim3(256), 0, stream, out_p, labels, io4, hm4,
                       gtpart, gtiou, pd_gou, pd_iou, conf_a, pgpart, hmpart, ticket);
    hipLaunchKernelGGL(kD, dim3(NBATCH), dim3(256), 0, stream, out_p, labels,
                       gtpart, gtiou, pd_gou, pd_iou, conf_a, pgpart, hmpart,
                       bacc, ticket, o);
}

// Round 10
// 48.856 us; speedup vs baseline: 5.2137x; 1.1735x over previous
//
#include <hip/hip_runtime.h>

#define NBATCH 16
#define NANCH  3
#define NGRID  64
#define NT     60
#define NPB    (NANCH*NGRID*NGRID)   // 12288 cells per batch
#define NCELL  (NBATCH*NPB)          // 196608 total cells
#define NLBL   (NBATCH*NT)           // 960 labels
#define NBPB   (NPB/256)             // 48 cell-blocks per batch
#define NBLKB  (NBATCH*NBPB)         // 768 kB blocks
#define FEPS   1e-16f

__device__ __forceinline__ float frcp(float x) { return __builtin_amdgcn_rcpf(x); }
__device__ __forceinline__ float sigm(float x) { return frcp(1.0f + __expf(-x)); }

__device__ __forceinline__ float waveSum(float v) {
#pragma unroll
    for (int o = 32; o > 0; o >>= 1) v += __shfl_down(v, o, 64);
    return v;
}
__device__ __forceinline__ double waveSumD(double v) {
#pragma unroll
    for (int o = 32; o > 0; o >>= 1) v += __shfl_down(v, o, 64);
    return v;
}

__device__ __forceinline__ unsigned int ford(float f) {
    unsigned int u = __float_as_uint(f);
    return (u & 0x80000000u) ? ~u : (u | 0x80000000u);
}
__device__ __forceinline__ float ford_inv(unsigned int u) {
    unsigned int v = (u & 0x80000000u) ? (u & 0x7fffffffu) : ~u;
    return __uint_as_float(v);
}

// fused gou: iou - (ca-un)/(ca+eps) == (inter*ce - (ca-un)*ue) / (ue*ce)
// -> ONE v_rcp instead of two (trans ops are quarter-rate).
__device__ __forceinline__ float gou_f(float px1, float py1, float px2, float py2, float pa,
                                       float gx1, float gy1, float gx2, float gy2, float ga) {
    float iw = fmaxf(fminf(px2, gx2) - fmaxf(px1, gx1), 0.f);
    float ih = fmaxf(fminf(py2, gy2) - fmaxf(py1, gy1), 0.f);
    float inter = iw * ih;
    float un = pa + ga - inter;
    float cw = fmaxf(px2, gx2) - fminf(px1, gx1);
    float ch = fmaxf(py2, gy2) - fminf(py1, gy1);
    float ca = cw * ch;
    float ue = un + FEPS, ce = ca + FEPS;
    return (inter * ce - (ca - un) * ue) * frcp(ue * ce);
}
__device__ __forceinline__ float iou_f(float px1, float py1, float px2, float py2, float pa,
                                       float gx1, float gy1, float gx2, float gy2, float ga) {
    float iw = fmaxf(fminf(px2, gx2) - fmaxf(px1, gx1), 0.f);
    float ih = fmaxf(fminf(py2, gy2) - fmaxf(py1, gy1), 0.f);
    float inter = iw * ih;
    float un = pa + ga - inter;
    return inter * frcp(un + FEPS);
}

// ---------------------------------------------------------------------------
// Kernel B: 768 blocks, 256 cells each. Decode -> LDS; pd-side argmax over
// 60 GTs; gt-side lane-per-GT block winners + aux (iou, cf, pdg, pdi of the
// winner cell, read from LDS); block-local obj bits via 60-label occ scan;
// 8 per-block double partials (mask_-free base sums + pg + hm).
// No global atomics, no zero-init, no per-cell output arrays.
// ---------------------------------------------------------------------------
__global__ __launch_bounds__(256)
void kB(const float* __restrict__ out, const float* __restrict__ labels,
        const float4* __restrict__ io4, const float4* __restrict__ hm4,
        unsigned long long* __restrict__ gtpart, float4* __restrict__ gtaux,
        double* __restrict__ bpart, unsigned int* __restrict__ ticket) {
    int blk = blockIdx.x, thr = threadIdx.x;
    if (blk == 0 && thr == 0) *ticket = 0u;    // stream order: visible to kD

    int b = blk / NBPB;
    int s = blk - b * NBPB;
    int n = s * 256 + thr;                     // cell within batch
    int idx = b * NPB + n;
    int wave = thr >> 6, lane = thr & 63;

    __shared__ float4 G4[NT];
    __shared__ float  GA[NT];
    __shared__ float4 Bxy[256];
    __shared__ float  Bpa[256];
    __shared__ float  pdG[256], pdI[256], cfL[256];
    __shared__ unsigned long long W[4][NT];
    __shared__ unsigned int obits[8];          // block-local obj bits (256 cells)
    __shared__ int keys[NT];
    __shared__ float red[8][4];

    if (thr < 8) obits[thr] = 0u;
    if (thr < NT) {
        const float* lp = labels + (b * NT + thr) * 5;
        float gx = lp[1], gy = lp[2], gw = lp[3], gh = lp[4];
        G4[thr] = make_float4(gx - gw * 0.5f, gy - gh * 0.5f,
                              gx + gw * 0.5f, gy + gh * 0.5f);
        GA[thr] = gw * gh;
        keys[thr] = ((int)(gy * (float)NGRID) << 6) | (int)(gx * (float)NGRID);
    }

    int a = n >> 12, gj = (n >> 6) & 63, gi = n & 63;
    int base = ((b * NANCH * 5 + a * 5) * NGRID + gj) * NGRID + gi;
    float xs = sigm(out[base]);
    float ys = sigm(out[base + NGRID * NGRID]);
    float ws = sigm(out[base + 2 * NGRID * NGRID]);
    float hs = sigm(out[base + 3 * NGRID * NGRID]);
    float cf = sigm(out[base + 4 * NGRID * NGRID]);

    float bx = (xs + (float)gi) * (1.0f / NGRID);
    float by = (ys + (float)gj) * (1.0f / NGRID);
    float px1 = bx - ws * 0.5f, px2 = bx + ws * 0.5f;
    float py1 = by - hs * 0.5f, py2 = by + hs * 0.5f;
    float pa = ws * hs;

    Bxy[thr] = make_float4(px1, py1, px2, py2);
    Bpa[thr] = pa;
    cfL[thr] = cf;
    __syncthreads();                           // G4/GA/keys + boxes ready

    // block-local obj bits: occ scan over this batch's 60 labels
    if (thr < NT) {
        int key = keys[thr];
        int occ = 0;
        for (int i = 0; i < thr; ++i)
            if (keys[i] == key) occ++;
        if (occ < NANCH) {
            int cell = (occ << 12) | key;               // batch-local n
            int lc = cell - s * 256;
            if (lc >= 0 && lc < 256) atomicOr(&obits[lc >> 5], 1u << (lc & 31));
        }
    }

    // --- pd-side: argmax-t of fused gou (strict > = first-t ties), then one
    //     iou recompute at the winner t.
    float bg = -1e30f;
    int bt = 0;
    for (int t = 0; t < NT; ++t) {
        float4 g = G4[t];
        float gou = gou_f(px1, py1, px2, py2, pa, g.x, g.y, g.z, g.w, GA[t]);
        if (gou > bg) { bg = gou; bt = t; }
    }
    float4 gbt = G4[bt];
    float biou = iou_f(px1, py1, px2, py2, pa, gbt.x, gbt.y, gbt.z, gbt.w, GA[bt]);
    pdG[thr] = bg;
    pdI[thr] = biou;

    // --- gt-side: lane = GT t; wave scans its 64 cells via LDS broadcast.
    {
        int t = (lane < NT) ? lane : 0;
        float4 g = G4[t];
        float ga = GA[t];
        int cbase = wave * 64;
        int nbase = s * 256 + cbase;
        unsigned long long bp = 0ull;
#pragma unroll 4
        for (int i = 0; i < 64; ++i) {
            float4 p = Bxy[cbase + i];         // wave-uniform address: broadcast
            float cpa = Bpa[cbase + i];
            float gou = gou_f(p.x, p.y, p.z, p.w, cpa, g.x, g.y, g.z, g.w, ga);
            unsigned long long pk = ((unsigned long long)ford(gou) << 32)
                                  | (0xFFFFFFFFu - (unsigned int)(nbase + i));
            if (pk > bp) bp = pk;              // ascending n + strict > = first-index
        }
        if (lane < NT) W[wave][lane] = bp;
    }
    __syncthreads();                           // W + pdG/pdI + obits complete

    // block winner per t -> gtpart + aux (iou_w, cf, pdg, pdi of winner cell)
    if (thr < NT) {
        unsigned long long pk = W[0][thr];
        if (W[1][thr] > pk) pk = W[1][thr];
        if (W[2][thr] > pk) pk = W[2][thr];
        if (W[3][thr] > pk) pk = W[3][thr];
        int wn = (int)(0xFFFFFFFFu - (unsigned int)(pk & 0xFFFFFFFFu));
        int lc = wn - s * 256;
        float4 p = Bxy[lc];
        float4 g = G4[thr];
        float iw = iou_f(p.x, p.y, p.z, p.w, Bpa[lc], g.x, g.y, g.z, g.w, GA[thr]);
        gtpart[blk * 64 + thr] = pk;
        gtaux [blk * 64 + thr] = make_float4(iw, cfL[lc], pdG[lc], pdI[lc]);
    }

    // --- 8 per-block partials: mask_-free base sums + pg + hm
    bool mk = (biou >= 0.5f);
    bool ob = (obits[thr >> 5] >> (thr & 31)) & 1u;
    float fmk = mk ? 1.f : 0.f, fnmk = 1.f - fmk, fob = ob ? 1.f : 0.f;
    float4 ha = io4[idx], hb = hm4[idx];
    float d0 = ha.x - hb.x, d1 = ha.y - hb.y, d2 = ha.z - hb.z, d3 = ha.w - hb.w;
    float vals[8] = {
        fmk,                          // c2 base  (sum mk)
        (1.f - bg) * fmk,             // sg base
        (1.f - biou) * fmk,           // si base
        cf * fob * fnmk,              // sint base (cf*ob*!mk)
        cf * cf * fnmk,               // spa base  (cf^2*!mk)
        fob * fnmk,                   // sga base  (ob*!mk)
        cf * cf,                      // pg
        d0 * d0 + d1 * d1 + d2 * d2 + d3 * d3   // hm
    };
#pragma unroll
    for (int k = 0; k < 8; ++k) {
        float vv = waveSum(vals[k]);
        if (lane == 0) red[k][wave] = vv;
    }
    __syncthreads();
    if (thr == 0) {
#pragma unroll
        for (int k = 0; k < 8; ++k)
            bpart[blk * 8 + k] = (double)(red[k][0] + red[k][1] + red[k][2] + red[k][3]);
    }
}

// ---------------------------------------------------------------------------
// Kernel D (slim): 16 blocks. Label pass (occ scan, loss_xy/wh/ig/cnt, full
// batch obj bits); 60x48 winner scan; dedup'd winner-cell corrections:
//   dc2=!mk, dsg=(1-pdg)!mk, dsi=(1-pdi)!mk, dsint=cf(1-ob*!mk),
//   dspa=cf^2*mk, dsga=1-ob*!mk      (per unique winner cell)
// 48-row partial sum; bacc row + fence + ticket; last block finalizes.
// ---------------------------------------------------------------------------
__global__ __launch_bounds__(256)
void kD(const float* __restrict__ out, const float* __restrict__ labels,
        const unsigned long long* __restrict__ gtpart, const float4* __restrict__ gtaux,
        const double* __restrict__ bpart,
        double* __restrict__ bacc, unsigned int* __restrict__ ticket,
        float* __restrict__ outp) {
    int b = blockIdx.x, thr = threadIdx.x;
    int wave = thr >> 6, lane = thr & 63;

    __shared__ int keys[NT];
    __shared__ unsigned int obits[NPB / 32];   // 384 words (full batch)
    __shared__ int wnL[NT];
    __shared__ float4 auxL[NT];
    __shared__ int finS;
    __shared__ double baccL[256];

    for (int w = thr; w < NPB / 32; w += 256) obits[w] = 0u;
    if (thr < NT) {
        const float* lp = labels + (b * NT + thr) * 5;
        keys[thr] = ((int)(lp[2] * (float)NGRID) << 6) | (int)(lp[1] * (float)NGRID);
    }
    __syncthreads();

    float sxy = 0.f, swh = 0.f, sig_ = 0.f, scnt = 0.f, sgou = 0.f, siou = 0.f;
    if (thr < NT) {
        // label pass
        int key = keys[thr];
        int occ = 0;
        for (int i = 0; i < thr; ++i)
            if (keys[i] == key) occ++;
        const float* lp = labels + (b * NT + thr) * 5;
        float bxf = lp[1] * (float)NGRID;
        float byf = lp[2] * (float)NGRID;
        float lw_ = lp[3], lh_ = lp[4];
        int gi = (int)bxf, gj = (int)byf;
        if (occ < NANCH) {
            int cell = (occ << 12) | (gj << 6) | gi;
            atomicOr(&obits[cell >> 5], 1u << (cell & 31));
            int base = ((b * NANCH * 5 + occ * 5) * NGRID + gj) * NGRID + gi;
            float xs = sigm(out[base]);
            float ys = sigm(out[base + NGRID * NGRID]);
            float ws = sigm(out[base + 2 * NGRID * NGRID]);
            float hs = sigm(out[base + 3 * NGRID * NGRID]);
            float cfl = sigm(out[base + 4 * NGRID * NGRID]);
            float tx = bxf - floorf(bxf);
            float ty = byf - floorf(byf);
            float dx = xs - tx, dy = ys - ty;
            sxy = dx * dx + dy * dy;
            float dw = __logf(ws) - __logf(lw_);
            float dh = __logf(hs) - __logf(lh_);
            swh = dw * dw + dh * dh;
            sig_ = cfl;
            scnt = 1.f;
        }
        // winner scan over this batch's 48 block winners for GT thr
        unsigned long long bestp = 0ull;
        int sbest = 0;
        for (int ss = 0; ss < NBPB; ++ss) {
            unsigned long long pk = gtpart[(b * NBPB + ss) * 64 + thr];
            if (pk > bestp) { bestp = pk; sbest = ss; }   // pk unique across ss
        }
        float4 aux = gtaux[(b * NBPB + sbest) * 64 + thr];
        wnL[thr] = (int)(0xFFFFFFFFu - (unsigned int)(bestp & 0xFFFFFFFFu));
        auxL[thr] = aux;
        sgou = 1.f - ford_inv((unsigned int)(bestp >> 32));
        siou = 1.f - aux.x;
    }
    __syncthreads();   // obits + wnL/auxL complete

    // dedup'd winner-cell corrections (first t claims the cell)
    float dc2 = 0.f, dsg = 0.f, dsi = 0.f, dsint = 0.f, dspa = 0.f, dsga = 0.f;
    if (thr < NT) {
        int wn = wnL[thr];
        bool uniq = true;
        for (int tp = 0; tp < thr; ++tp)
            if (wnL[tp] == wn) { uniq = false; break; }
        if (uniq) {
            float4 aux = auxL[thr];            // (iou_w, cf, pdg, pdi)
            bool mk = (aux.w >= 0.5f);
            bool ob = (obits[wn >> 5] >> (wn & 31)) & 1u;
            float fnmk = mk ? 0.f : 1.f;
            float obnmk = (ob ? 1.f : 0.f) * fnmk;
            dc2 = fnmk;
            dsg = (1.f - aux.z) * fnmk;
            dsi = (1.f - aux.w) * fnmk;
            dsint = aux.y * (1.f - obnmk);
            dspa = aux.y * aux.y * (mk ? 1.f : 0.f);
            dsga = 1.f - obnmk;
        }
    }

    // wave-0 reductions + 48-row partial sums
    double labD[6], corD[6], prtD[8];
    if (wave == 0) {
        labD[0] = (double)waveSum(sxy);
        labD[1] = (double)waveSum(swh);
        labD[2] = (double)waveSum(sig_);
        labD[3] = (double)waveSum(scnt);
        labD[4] = (double)waveSum(sgou);
        labD[5] = (double)waveSum(siou);
        corD[0] = (double)waveSum(dc2);
        corD[1] = (double)waveSum(dsg);
        corD[2] = (double)waveSum(dsi);
        corD[3] = (double)waveSum(dsint);
        corD[4] = (double)waveSum(dspa);
        corD[5] = (double)waveSum(dsga);
#pragma unroll
        for (int k = 0; k < 8; ++k) {
            double v = (lane < NBPB) ? bpart[(b * NBPB + lane) * 8 + k] : 0.0;
            prtD[k] = waveSumD(v);
        }
    }
    __syncthreads();

    // bacc row + release fence + ticket
    if (thr == 0) {
        double* row = &bacc[b * 16];
        row[0]  = prtD[0] + corD[0];   // c2
        row[1]  = prtD[1] + corD[1];   // sg
        row[2]  = prtD[2] + corD[2];   // si
        row[3]  = prtD[3] + corD[3];   // sinter
        row[4]  = prtD[4] + corD[4];   // spa
        row[5]  = prtD[5] + corD[5];   // sga
        row[6]  = labD[4];             // sgou
        row[7]  = labD[5];             // siou
        row[8]  = labD[0];             // sxy
        row[9]  = labD[1];             // swh
        row[10] = labD[2];             // ig
        row[11] = labD[3];             // cnt
        row[12] = prtD[6];             // pg
        row[13] = prtD[7];             // hm
        row[14] = 0.0; row[15] = 0.0;
        __threadfence();
        unsigned int old = atomicAdd(ticket, 1u);
        finS = (old == NBATCH - 1) ? 1 : 0;
    }
    __syncthreads();

    // finalize (last-finishing block; block-uniform branch)
    if (finS) {
        int bb = thr >> 4, k = thr & 15;
        baccL[thr] = atomicAdd(&bacc[bb * 16 + k], 0.0);   // coherent RMW read
        __syncthreads();
        if (thr == 0) {
            double cnt = 0, sxyT = 0, swhT = 0, igT = 0, pgT = 0, hmT = 0;
            double sgouT = 0, siouT = 0, gou2 = 0, iou2 = 0, confbT = 0;
            for (int q = 0; q < NBATCH; ++q) {
                const double* r = &baccL[q * 16];
                cnt += r[11]; sxyT += r[8]; swhT += r[9]; igT += r[10];
                pgT += r[12]; hmT += r[13];
                sgouT += r[6]; siouT += r[7];
                gou2 += r[1] / r[0];
                iou2 += r[2] / r[0];
                confbT += 1.0 - (2.0 * r[3] + 1.0) / (r[4] + r[5] + 1.0);
            }
            double lxy = sxyT / cnt;
            double lwh = swhT / cnt;
            double lgou = sgouT / (double)NLBL + gou2 / (double)NBATCH;
            double liou = siouT / (double)NLBL + iou2 / (double)NBATCH;
            double dice = (2.0 * igT + 1.0) / (pgT + cnt + 1.0);
            if (dice != dice) dice = 1.0;
            double lconf = 1.0 - dice + confbT / (double)NBATCH;
            double total = lxy + lwh + lconf + lgou;
            double hmv = hmT / (double)(4 * NCELL);
            outp[0] = (float)lxy;
            outp[1] = (float)lwh;
            outp[2] = (float)lconf;
            outp[3] = (float)liou;
            outp[4] = (float)lgou;
            outp[5] = (float)total;
            outp[6] = (float)hmv;
        }
    }
}

// ---------------------------------------------------------------------------
extern "C" void kernel_launch(void* const* d_in, const int* in_sizes, int n_in,
                              void* d_out, int out_size, void* d_ws, size_t ws_size,
                              hipStream_t stream) {
    const float* out_p  = (const float*)d_in[0];
    const float* labels = (const float*)d_in[1];
    const float4* io4   = (const float4*)d_in[2];
    const float4* hm4   = (const float4*)d_in[3];
    float* o = (float*)d_out;

    char* ws = (char*)d_ws;
    unsigned long long* gtpart = (unsigned long long*)(ws);            // 393216 B
    float4* gtaux = (float4*)(ws + 393216);                            // 786432 B
    double* bpart = (double*)(ws + 1179648);                           //  49152 B
    double* bacc  = (double*)(ws + 1228800);                           //   2048 B
    unsigned int* ticket = (unsigned int*)(ws + 1230848);              //     64 B
    // ~1.23 MB total; all consumed data fully written each call (kB zeroes
    // the ticket) — no memset, no zero-init ordering hazards.

    hipLaunchKernelGGL(kB, dim3(NBLKB), dim3(256), 0, stream, out_p, labels, io4, hm4,
                       gtpart, gtaux, bpart, ticket);
    hipLaunchKernelGGL(kD, dim3(NBATCH), dim3(256), 0, stream, out_p, labels,
                       gtpart, gtaux, bpart, bacc, ticket, o);
}

// Round 13
// 47.654 us; speedup vs baseline: 5.3452x; 1.0252x over previous
//
#include <hip/hip_runtime.h>

#define NBATCH 16
#define NANCH  3
#define NGRID  64
#define NT     60
#define NPB    (NANCH*NGRID*NGRID)   // 12288 cells per batch
#define NCELL  (NBATCH*NPB)          // 196608 total cells
#define NLBL   (NBATCH*NT)           // 960 labels
#define NBPB   (NPB/256)             // 48 cell-blocks per batch
#define NBLKB  (NBATCH*NBPB)         // 768 kB blocks
#define FEPS   1e-16f

__device__ __forceinline__ float frcp(float x) { return __builtin_amdgcn_rcpf(x); }
__device__ __forceinline__ float sigm(float x) { return frcp(1.0f + __expf(-x)); }

__device__ __forceinline__ float waveSum(float v) {
#pragma unroll
    for (int o = 32; o > 0; o >>= 1) v += __shfl_down(v, o, 64);
    return v;
}
__device__ __forceinline__ double waveSumD(double v) {
#pragma unroll
    for (int o = 32; o > 0; o >>= 1) v += __shfl_down(v, o, 64);
    return v;
}

__device__ __forceinline__ unsigned int ford(float f) {
    unsigned int u = __float_as_uint(f);
    return (u & 0x80000000u) ? ~u : (u | 0x80000000u);
}
__device__ __forceinline__ float ford_inv(unsigned int u) {
    unsigned int v = (u & 0x80000000u) ? (u & 0x7fffffffu) : ~u;
    return __uint_as_float(v);
}

// fused gou: iou - (ca-un)/(ca+eps) == (inter*ce - (ca-un)*ue) / (ue*ce)
// -> ONE v_rcp instead of two (trans ops are quarter-rate).
__device__ __forceinline__ float gou_f(float px1, float py1, float px2, float py2, float pa,
                                       float gx1, float gy1, float gx2, float gy2, float ga) {
    float iw = fmaxf(fminf(px2, gx2) - fmaxf(px1, gx1), 0.f);
    float ih = fmaxf(fminf(py2, gy2) - fmaxf(py1, gy1), 0.f);
    float inter = iw * ih;
    float un = pa + ga - inter;
    float cw = fmaxf(px2, gx2) - fminf(px1, gx1);
    float ch = fmaxf(py2, gy2) - fminf(py1, gy1);
    float ca = cw * ch;
    float ue = un + FEPS, ce = ca + FEPS;
    return (inter * ce - (ca - un) * ue) * frcp(ue * ce);
}
__device__ __forceinline__ float iou_f(float px1, float py1, float px2, float py2, float pa,
                                       float gx1, float gy1, float gx2, float gy2, float ga) {
    float iw = fmaxf(fminf(px2, gx2) - fmaxf(px1, gx1), 0.f);
    float ih = fmaxf(fminf(py2, gy2) - fmaxf(py1, gy1), 0.f);
    float inter = iw * ih;
    float un = pa + ga - inter;
    return inter * frcp(un + FEPS);
}

// ---------------------------------------------------------------------------
// Kernel B: 768 blocks, 256 cells each (r10-proven structure + exact
// dual-chain ILP split in both hot loops). Decode -> LDS; pd-side argmax
// over 60 GTs; gt-side lane-per-GT block winners + aux; block-local obj
// bits; 8 per-block double partials. No global atomics, no zero-init.
// ---------------------------------------------------------------------------
__global__ __launch_bounds__(256)
void kB(const float* __restrict__ out, const float* __restrict__ labels,
        const float4* __restrict__ io4, const float4* __restrict__ hm4,
        unsigned long long* __restrict__ gtpart, float4* __restrict__ gtaux,
        double* __restrict__ bpart, unsigned int* __restrict__ ticket) {
    int blk = blockIdx.x, thr = threadIdx.x;
    if (blk == 0 && thr == 0) *ticket = 0u;    // stream order: visible to kD

    int b = blk / NBPB;
    int s = blk - b * NBPB;
    int n = s * 256 + thr;                     // cell within batch
    int idx = b * NPB + n;
    int wave = thr >> 6, lane = thr & 63;

    __shared__ float4 G4[NT];
    __shared__ float  GA[NT];
    __shared__ float4 Bxy[256];
    __shared__ float  Bpa[256];
    __shared__ float  pdG[256], pdI[256], cfL[256];
    __shared__ unsigned long long W[4][NT];
    __shared__ unsigned int obits[8];          // block-local obj bits (256 cells)
    __shared__ int keys[NT];
    __shared__ float red[8][4];

    if (thr < 8) obits[thr] = 0u;
    if (thr < NT) {
        const float* lp = labels + (b * NT + thr) * 5;
        float gx = lp[1], gy = lp[2], gw = lp[3], gh = lp[4];
        G4[thr] = make_float4(gx - gw * 0.5f, gy - gh * 0.5f,
                              gx + gw * 0.5f, gy + gh * 0.5f);
        GA[thr] = gw * gh;
        keys[thr] = ((int)(gy * (float)NGRID) << 6) | (int)(gx * (float)NGRID);
    }

    int a = n >> 12, gj = (n >> 6) & 63, gi = n & 63;
    int base = ((b * NANCH * 5 + a * 5) * NGRID + gj) * NGRID + gi;
    float xs = sigm(out[base]);
    float ys = sigm(out[base + NGRID * NGRID]);
    float ws = sigm(out[base + 2 * NGRID * NGRID]);
    float hs = sigm(out[base + 3 * NGRID * NGRID]);
    float cf = sigm(out[base + 4 * NGRID * NGRID]);

    float bx = (xs + (float)gi) * (1.0f / NGRID);
    float by = (ys + (float)gj) * (1.0f / NGRID);
    float px1 = bx - ws * 0.5f, px2 = bx + ws * 0.5f;
    float py1 = by - hs * 0.5f, py2 = by + hs * 0.5f;
    float pa = ws * hs;

    Bxy[thr] = make_float4(px1, py1, px2, py2);
    Bpa[thr] = pa;
    cfL[thr] = cf;
    __syncthreads();                           // G4/GA/keys + boxes ready

    // block-local obj bits: occ scan over this batch's 60 labels
    if (thr < NT) {
        int key = keys[thr];
        int occ = 0;
        for (int i = 0; i < thr; ++i)
            if (keys[i] == key) occ++;
        if (occ < NANCH) {
            int cell = (occ << 12) | key;               // batch-local n
            int lc = cell - s * 256;
            if (lc >= 0 && lc < 256) atomicOr(&obits[lc >> 5], 1u << (lc & 31));
        }
    }

    // --- pd-side: argmax-t of fused gou, TWO independent half-range chains
    // (exact: within-half strict > = first-t; cross-half merge only replaces
    // on strict >, and all t in half 1 exceed all t in half 0).
    float bg0 = -1e30f, bg1 = -1e30f;
    int bt0 = 0, bt1 = NT / 2;
#pragma unroll 2
    for (int t = 0; t < NT / 2; ++t) {
        float4 ga0 = G4[t];
        float g0 = gou_f(px1, py1, px2, py2, pa, ga0.x, ga0.y, ga0.z, ga0.w, GA[t]);
        if (g0 > bg0) { bg0 = g0; bt0 = t; }
        float4 ga1 = G4[t + NT / 2];
        float g1 = gou_f(px1, py1, px2, py2, pa, ga1.x, ga1.y, ga1.z, ga1.w, GA[t + NT / 2]);
        if (g1 > bg1) { bg1 = g1; bt1 = t + NT / 2; }
    }
    float bg = bg0;
    int bt = bt0;
    if (bg1 > bg0) { bg = bg1; bt = bt1; }
    float4 gbt = G4[bt];
    float biou = iou_f(px1, py1, px2, py2, pa, gbt.x, gbt.y, gbt.z, gbt.w, GA[bt]);
    pdG[thr] = bg;
    pdI[thr] = biou;

    // --- gt-side: lane = GT t; wave scans its 64 cells via LDS broadcast.
    // TWO independent packed-u64 chains merged by max — bit-exact (tie-break
    // is embedded in the key, max is associative).
    {
        int t = (lane < NT) ? lane : 0;
        float4 g = G4[t];
        float ga = GA[t];
        int cbase = wave * 64;
        int nbase = s * 256 + cbase;
        unsigned long long bp0 = 0ull, bp1 = 0ull;
#pragma unroll 4
        for (int i = 0; i < 32; ++i) {
            float4 p0 = Bxy[cbase + i];
            float gou0 = gou_f(p0.x, p0.y, p0.z, p0.w, Bpa[cbase + i],
                               g.x, g.y, g.z, g.w, ga);
            unsigned long long pk0 = ((unsigned long long)ford(gou0) << 32)
                                   | (0xFFFFFFFFu - (unsigned int)(nbase + i));
            if (pk0 > bp0) bp0 = pk0;
            float4 p1 = Bxy[cbase + 32 + i];
            float gou1 = gou_f(p1.x, p1.y, p1.z, p1.w, Bpa[cbase + 32 + i],
                               g.x, g.y, g.z, g.w, ga);
            unsigned long long pk1 = ((unsigned long long)ford(gou1) << 32)
                                   | (0xFFFFFFFFu - (unsigned int)(nbase + 32 + i));
            if (pk1 > bp1) bp1 = pk1;
        }
        unsigned long long bp = (bp1 > bp0) ? bp1 : bp0;
        if (lane < NT) W[wave][lane] = bp;
    }
    __syncthreads();                           // W + pdG/pdI + obits complete

    // block winner per t -> gtpart + aux (iou_w, cf, pdg, pdi of winner cell)
    if (thr < NT) {
        unsigned long long pk = W[0][thr];
        if (W[1][thr] > pk) pk = W[1][thr];
        if (W[2][thr] > pk) pk = W[2][thr];
        if (W[3][thr] > pk) pk = W[3][thr];
        int wn = (int)(0xFFFFFFFFu - (unsigned int)(pk & 0xFFFFFFFFu));
        int lc = wn - s * 256;
        float4 p = Bxy[lc];
        float4 g = G4[thr];
        float iw = iou_f(p.x, p.y, p.z, p.w, Bpa[lc], g.x, g.y, g.z, g.w, GA[thr]);
        gtpart[blk * 64 + thr] = pk;
        gtaux [blk * 64 + thr] = make_float4(iw, cfL[lc], pdG[lc], pdI[lc]);
    }

    // --- 8 per-block partials: mask_-free base sums + pg + hm
    bool mk = (biou >= 0.5f);
    bool ob = (obits[thr >> 5] >> (thr & 31)) & 1u;
    float fmk = mk ? 1.f : 0.f, fnmk = 1.f - fmk, fob = ob ? 1.f : 0.f;
    float4 ha = io4[idx], hb = hm4[idx];
    float d0 = ha.x - hb.x, d1 = ha.y - hb.y, d2 = ha.z - hb.z, d3 = ha.w - hb.w;
    float vals[8] = {
        fmk,                          // c2 base  (sum mk)
        (1.f - bg) * fmk,             // sg base
        (1.f - biou) * fmk,           // si base
        cf * fob * fnmk,              // sint base (cf*ob*!mk)
        cf * cf * fnmk,               // spa base  (cf^2*!mk)
        fob * fnmk,                   // sga base  (ob*!mk)
        cf * cf,                      // pg
        d0 * d0 + d1 * d1 + d2 * d2 + d3 * d3   // hm
    };
#pragma unroll
    for (int k = 0; k < 8; ++k) {
        float vv = waveSum(vals[k]);
        if (lane == 0) red[k][wave] = vv;
    }
    __syncthreads();
    if (thr == 0) {
#pragma unroll
        for (int k = 0; k < 8; ++k)
            bpart[blk * 8 + k] = (double)(red[k][0] + red[k][1] + red[k][2] + red[k][3]);
    }
}

// ---------------------------------------------------------------------------
// Kernel D (slim, r10-proven): 16 blocks. Label pass (occ scan, loss_xy/wh/
// ig/cnt, full batch obj bits); 60x48 winner scan; dedup'd winner-cell
// corrections; 48-row partial sum; bacc row + fence + ticket; last block
// finalizes. Cross-kernel boundary provides producer->consumer coherence.
// ---------------------------------------------------------------------------
__global__ __launch_bounds__(256)
void kD(const float* __restrict__ out, const float* __restrict__ labels,
        const unsigned long long* __restrict__ gtpart, const float4* __restrict__ gtaux,
        const double* __restrict__ bpart,
        double* __restrict__ bacc, unsigned int* __restrict__ ticket,
        float* __restrict__ outp) {
    int b = blockIdx.x, thr = threadIdx.x;
    int wave = thr >> 6, lane = thr & 63;

    __shared__ int keys[NT];
    __shared__ unsigned int obits[NPB / 32];   // 384 words (full batch)
    __shared__ int wnL[NT];
    __shared__ float4 auxL[NT];
    __shared__ int finS;
    __shared__ double baccL[256];

    for (int w = thr; w < NPB / 32; w += 256) obits[w] = 0u;
    if (thr < NT) {
        const float* lp = labels + (b * NT + thr) * 5;
        keys[thr] = ((int)(lp[2] * (float)NGRID) << 6) | (int)(lp[1] * (float)NGRID);
    }
    __syncthreads();

    float sxy = 0.f, swh = 0.f, sig_ = 0.f, scnt = 0.f, sgou = 0.f, siou = 0.f;
    if (thr < NT) {
        // label pass
        int key = keys[thr];
        int occ = 0;
        for (int i = 0; i < thr; ++i)
            if (keys[i] == key) occ++;
        const float* lp = labels + (b * NT + thr) * 5;
        float bxf = lp[1] * (float)NGRID;
        float byf = lp[2] * (float)NGRID;
        float lw_ = lp[3], lh_ = lp[4];
        int gi = (int)bxf, gj = (int)byf;
        if (occ < NANCH) {
            int cell = (occ << 12) | (gj << 6) | gi;
            atomicOr(&obits[cell >> 5], 1u << (cell & 31));
            int base = ((b * NANCH * 5 + occ * 5) * NGRID + gj) * NGRID + gi;
            float xs = sigm(out[base]);
            float ys = sigm(out[base + NGRID * NGRID]);
            float ws = sigm(out[base + 2 * NGRID * NGRID]);
            float hs = sigm(out[base + 3 * NGRID * NGRID]);
            float cfl = sigm(out[base + 4 * NGRID * NGRID]);
            float tx = bxf - floorf(bxf);
            float ty = byf - floorf(byf);
            float dx = xs - tx, dy = ys - ty;
            sxy = dx * dx + dy * dy;
            float dw = __logf(ws) - __logf(lw_);
            float dh = __logf(hs) - __logf(lh_);
            swh = dw * dw + dh * dh;
            sig_ = cfl;
            scnt = 1.f;
        }
        // winner scan over this batch's 48 block winners for GT thr
        unsigned long long bestp = 0ull;
        int sbest = 0;
        for (int ss = 0; ss < NBPB; ++ss) {
            unsigned long long pk = gtpart[(b * NBPB + ss) * 64 + thr];
            if (pk > bestp) { bestp = pk; sbest = ss; }   // pk unique across ss
        }
        float4 aux = gtaux[(b * NBPB + sbest) * 64 + thr];
        wnL[thr] = (int)(0xFFFFFFFFu - (unsigned int)(bestp & 0xFFFFFFFFu));
        auxL[thr] = aux;
        sgou = 1.f - ford_inv((unsigned int)(bestp >> 32));
        siou = 1.f - aux.x;
    }
    __syncthreads();   // obits + wnL/auxL complete

    // dedup'd winner-cell corrections (first t claims the cell)
    float dc2 = 0.f, dsg = 0.f, dsi = 0.f, dsint = 0.f, dspa = 0.f, dsga = 0.f;
    if (thr < NT) {
        int wn = wnL[thr];
        bool uniq = true;
        for (int tp = 0; tp < thr; ++tp)
            if (wnL[tp] == wn) { uniq = false; break; }
        if (uniq) {
            float4 aux = auxL[thr];            // (iou_w, cf, pdg, pdi)
            bool mk = (aux.w >= 0.5f);
            bool ob = (obits[wn >> 5] >> (wn & 31)) & 1u;
            float fnmk = mk ? 0.f : 1.f;
            float obnmk = (ob ? 1.f : 0.f) * fnmk;
            dc2 = fnmk;
            dsg = (1.f - aux.z) * fnmk;
            dsi = (1.f - aux.w) * fnmk;
            dsint = aux.y * (1.f - obnmk);
            dspa = aux.y * aux.y * (mk ? 1.f : 0.f);
            dsga = 1.f - obnmk;
        }
    }

    // wave-0 reductions + 48-row partial sums
    double labD[6], corD[6], prtD[8];
    if (wave == 0) {
        labD[0] = (double)waveSum(sxy);
        labD[1] = (double)waveSum(swh);
        labD[2] = (double)waveSum(sig_);
        labD[3] = (double)waveSum(scnt);
        labD[4] = (double)waveSum(sgou);
        labD[5] = (double)waveSum(siou);
        corD[0] = (double)waveSum(dc2);
        corD[1] = (double)waveSum(dsg);
        corD[2] = (double)waveSum(dsi);
        corD[3] = (double)waveSum(dsint);
        corD[4] = (double)waveSum(dspa);
        corD[5] = (double)waveSum(dsga);
#pragma unroll
        for (int k = 0; k < 8; ++k) {
            double v = (lane < NBPB) ? bpart[(b * NBPB + lane) * 8 + k] : 0.0;
            prtD[k] = waveSumD(v);
        }
    }
    __syncthreads();

    // bacc row + release fence + ticket
    if (thr == 0) {
        double* row = &bacc[b * 16];
        row[0]  = prtD[0] + corD[0];   // c2
        row[1]  = prtD[1] + corD[1];   // sg
        row[2]  = prtD[2] + corD[2];   // si
        row[3]  = prtD[3] + corD[3];   // sinter
        row[4]  = prtD[4] + corD[4];   // spa
        row[5]  = prtD[5] + corD[5];   // sga
        row[6]  = labD[4];             // sgou
        row[7]  = labD[5];             // siou
        row[8]  = labD[0];             // sxy
        row[9]  = labD[1];             // swh
        row[10] = labD[2];             // ig
        row[11] = labD[3];             // cnt
        row[12] = prtD[6];             // pg
        row[13] = prtD[7];             // hm
        row[14] = 0.0; row[15] = 0.0;
        __threadfence();
        unsigned int old = atomicAdd(ticket, 1u);
        finS = (old == NBATCH - 1) ? 1 : 0;
    }
    __syncthreads();

    // finalize (last-finishing block; block-uniform branch)
    if (finS) {
        int bb = thr >> 4, k = thr & 15;
        baccL[thr] = atomicAdd(&bacc[bb * 16 + k], 0.0);   // coherent RMW read
        __syncthreads();
        if (thr == 0) {
            double cnt = 0, sxyT = 0, swhT = 0, igT = 0, pgT = 0, hmT = 0;
            double sgouT = 0, siouT = 0, gou2 = 0, iou2 = 0, confbT = 0;
            for (int q = 0; q < NBATCH; ++q) {
                const double* r = &baccL[q * 16];
                cnt += r[11]; sxyT += r[8]; swhT += r[9]; igT += r[10];
                pgT += r[12]; hmT += r[13];
                sgouT += r[6]; siouT += r[7];
                gou2 += r[1] / r[0];
                iou2 += r[2] / r[0];
                confbT += 1.0 - (2.0 * r[3] + 1.0) / (r[4] + r[5] + 1.0);
            }
            double lxy = sxyT / cnt;
            double lwh = swhT / cnt;
            double lgou = sgouT / (double)NLBL + gou2 / (double)NBATCH;
            double liou = siouT / (double)NLBL + iou2 / (double)NBATCH;
            double dice = (2.0 * igT + 1.0) / (pgT + cnt + 1.0);
            if (dice != dice) dice = 1.0;
            double lconf = 1.0 - dice + confbT / (double)NBATCH;
            double total = lxy + lwh + lconf + lgou;
            double hmv = hmT / (double)(4 * NCELL);
            outp[0] = (float)lxy;
            outp[1] = (float)lwh;
            outp[2] = (float)lconf;
            outp[3] = (float)liou;
            outp[4] = (float)lgou;
            outp[5] = (float)total;
            outp[6] = (float)hmv;
        }
    }
}

// ---------------------------------------------------------------------------
extern "C" void kernel_launch(void* const* d_in, const int* in_sizes, int n_in,
                              void* d_out, int out_size, void* d_ws, size_t ws_size,
                              hipStream_t stream) {
    const float* out_p  = (const float*)d_in[0];
    const float* labels = (const float*)d_in[1];
    const float4* io4   = (const float4*)d_in[2];
    const float4* hm4   = (const float4*)d_in[3];
    float* o = (float*)d_out;

    char* ws = (char*)d_ws;
    unsigned long long* gtpart = (unsigned long long*)(ws);            // 393216 B
    float4* gtaux = (float4*)(ws + 393216);                            // 786432 B
    double* bpart = (double*)(ws + 1179648);                           //  49152 B
    double* bacc  = (double*)(ws + 1228800);                           //   2048 B
    unsigned int* ticket = (unsigned int*)(ws + 1230848);              //     64 B
    // ~1.23 MB total; all consumed data fully written each call (kB zeroes
    // the ticket) — no memset, no zero-init ordering hazards. Producer ->
    // consumer crosses the kernel boundary (the only coherence mechanism
    // proven on this chip: r11/r12 intra-dispatch attempts both failed).

    hipLaunchKernelGGL(kB, dim3(NBLKB), dim3(256), 0, stream, out_p, labels, io4, hm4,
                       gtpart, gtaux, bpart, ticket);
    hipLaunchKernelGGL(kD, dim3(NBATCH), dim3(256), 0, stream, out_p, labels,
                       gtpart, gtaux, bpart, bacc, ticket, o);
}

// Round 14
// 39.938 us; speedup vs baseline: 6.3779x; 1.1932x over previous
//
#include <hip/hip_runtime.h>

#define NBATCH 16
#define NANCH  3
#define NGRID  64
#define NT     60
#define NPB    (NANCH*NGRID*NGRID)   // 12288 cells per batch
#define NCELL  (NBATCH*NPB)          // 196608 total cells
#define NLBL   (NBATCH*NT)           // 960 labels
#define NBPB   (NPB/256)             // 48 cell-blocks per batch
#define NBLKB  (NBATCH*NBPB)         // 768 kB blocks
#define FEPS   1e-16f

__device__ __forceinline__ float frcp(float x) { return __builtin_amdgcn_rcpf(x); }
__device__ __forceinline__ float sigm(float x) { return frcp(1.0f + __expf(-x)); }

__device__ __forceinline__ float waveSum(float v) {
#pragma unroll
    for (int o = 32; o > 0; o >>= 1) v += __shfl_down(v, o, 64);
    return v;
}
__device__ __forceinline__ double waveSumD(double v) {
#pragma unroll
    for (int o = 32; o > 0; o >>= 1) v += __shfl_down(v, o, 64);
    return v;
}

__device__ __forceinline__ unsigned int ford(float f) {
    unsigned int u = __float_as_uint(f);
    return (u & 0x80000000u) ? ~u : (u | 0x80000000u);
}
__device__ __forceinline__ float ford_inv(unsigned int u) {
    unsigned int v = (u & 0x80000000u) ? (u & 0x7fffffffu) : ~u;
    return __uint_as_float(v);
}

// fused gou: iou - (ca-un)/(ca+eps) == (inter*ce - (ca-un)*ue) / (ue*ce)
__device__ __forceinline__ float gou_f(float px1, float py1, float px2, float py2, float pa,
                                       float gx1, float gy1, float gx2, float gy2, float ga) {
    float iw = fmaxf(fminf(px2, gx2) - fmaxf(px1, gx1), 0.f);
    float ih = fmaxf(fminf(py2, gy2) - fmaxf(py1, gy1), 0.f);
    float inter = iw * ih;
    float un = pa + ga - inter;
    float cw = fmaxf(px2, gx2) - fminf(px1, gx1);
    float ch = fmaxf(py2, gy2) - fminf(py1, gy1);
    float ca = cw * ch;
    float ue = un + FEPS, ce = ca + FEPS;
    return (inter * ce - (ca - un) * ue) * frcp(ue * ce);
}
__device__ __forceinline__ float iou_f(float px1, float py1, float px2, float py2, float pa,
                                       float gx1, float gy1, float gx2, float gy2, float ga) {
    float iw = fmaxf(fminf(px2, gx2) - fmaxf(px1, gx1), 0.f);
    float ih = fmaxf(fminf(py2, gy2) - fmaxf(py1, gy1), 0.f);
    float inter = iw * ih;
    float un = pa + ga - inter;
    return inter * frcp(un + FEPS);
}

// ---------------------------------------------------------------------------
// Kernel B: 768 blocks, 256 cells each. EVAL-SHARING version: the gt-side
// lane-per-GT loop writes its gou values into an LDS matrix (two 128-cell
// half-tiles, row stride 61 => conflict-free writes AND reads); the pd-side
// then argmaxes over LDS READS instead of re-evaluating — eval count per
// thread drops 124 -> 64. Values bit-identical; gt-side scan-order change is
// argmax-over-same-set with order-independent packed keys.
// ---------------------------------------------------------------------------
__global__ __launch_bounds__(256)
void kB(const float* __restrict__ out, const float* __restrict__ labels,
        const float4* __restrict__ io4, const float4* __restrict__ hm4,
        unsigned long long* __restrict__ gtpart, float4* __restrict__ gtaux,
        double* __restrict__ bpart, unsigned int* __restrict__ ticket) {
    int blk = blockIdx.x, thr = threadIdx.x;
    if (blk == 0 && thr == 0) *ticket = 0u;    // stream order: visible to kD

    int b = blk / NBPB;
    int s = blk - b * NBPB;
    int n = s * 256 + thr;                     // cell within batch
    int idx = b * NPB + n;
    int wave = thr >> 6, lane = thr & 63;

    __shared__ float4 G4[NT];
    __shared__ float  GA[NT];
    __shared__ float4 Bxy[256];
    __shared__ float  Bpa[256];
    __shared__ float  GM[128][61];             // half-tile gou matrix (31.2 KB)
    __shared__ float  pdG[256], pdI[256], cfL[256];
    __shared__ unsigned long long W[4][NT];
    __shared__ unsigned int obits[8];          // block-local obj bits (256 cells)
    __shared__ int keys[NT];
    __shared__ float red[8][4];

    if (thr < 8) obits[thr] = 0u;
    if (thr < NT) {
        const float* lp = labels + (b * NT + thr) * 5;
        float gx = lp[1], gy = lp[2], gw = lp[3], gh = lp[4];
        G4[thr] = make_float4(gx - gw * 0.5f, gy - gh * 0.5f,
                              gx + gw * 0.5f, gy + gh * 0.5f);
        GA[thr] = gw * gh;
        keys[thr] = ((int)(gy * (float)NGRID) << 6) | (int)(gx * (float)NGRID);
    }

    int a = n >> 12, gj = (n >> 6) & 63, gi = n & 63;
    int base = ((b * NANCH * 5 + a * 5) * NGRID + gj) * NGRID + gi;
    float xs = sigm(out[base]);
    float ys = sigm(out[base + NGRID * NGRID]);
    float ws = sigm(out[base + 2 * NGRID * NGRID]);
    float hs = sigm(out[base + 3 * NGRID * NGRID]);
    float cf = sigm(out[base + 4 * NGRID * NGRID]);

    float bx = (xs + (float)gi) * (1.0f / NGRID);
    float by = (ys + (float)gj) * (1.0f / NGRID);
    float px1 = bx - ws * 0.5f, px2 = bx + ws * 0.5f;
    float py1 = by - hs * 0.5f, py2 = by + hs * 0.5f;
    float pa = ws * hs;

    Bxy[thr] = make_float4(px1, py1, px2, py2);
    Bpa[thr] = pa;
    cfL[thr] = cf;
    __syncthreads();                           // G4/GA/keys + boxes ready

    // block-local obj bits: occ scan over this batch's 60 labels
    if (thr < NT) {
        int key = keys[thr];
        int occ = 0;
        for (int i = 0; i < thr; ++i)
            if (keys[i] == key) occ++;
        if (occ < NANCH) {
            int cell = (occ << 12) | key;               // batch-local n
            int lc = cell - s * 256;
            if (lc >= 0 && lc < 256) atomicOr(&obits[lc >> 5], 1u << (lc & 31));
        }
    }

    // --- two half-tiles: gt-side eval (writes GM) then pd-side (reads GM)
    int t = (lane < NT) ? lane : 0;
    float4 gt4 = G4[t];
    float gta = GA[t];
    unsigned long long bp = 0ull;              // per-lane running gt winner
    float bg = -1e30f, biou = 0.0f;            // this thread's pd result

#pragma unroll
    for (int h = 0; h < 2; ++h) {
        // gt-side: wave scans 32 cells of half h via LDS broadcast; lane = t
        int cb = h * 128 + wave * 32;
        int nb = s * 256 + cb;
#pragma unroll 4
        for (int i = 0; i < 32; ++i) {
            int c = cb + i;
            float4 p = Bxy[c];                 // wave-uniform address: broadcast
            float cpa = Bpa[c];
            float gou = gou_f(p.x, p.y, p.z, p.w, cpa,
                              gt4.x, gt4.y, gt4.z, gt4.w, gta);
            if (lane < NT) GM[c - h * 128][lane] = gou;
            unsigned long long pk = ((unsigned long long)ford(gou) << 32)
                                  | (0xFFFFFFFFu - (unsigned int)(nb + i));
            if (pk > bp) bp = pk;              // ascending n + strict > = first-index
        }
        __syncthreads();                       // GM half complete

        // pd-side for this half's 128 cells: LDS reads, dual-chain argmax
        if ((thr >> 7) == h) {
            int lc = thr & 127;
            float bg0 = -1e30f, bg1 = -1e30f;
            int bt0 = 0, bt1 = NT / 2;
#pragma unroll 2
            for (int tt = 0; tt < NT / 2; ++tt) {
                float g0 = GM[lc][tt];
                if (g0 > bg0) { bg0 = g0; bt0 = tt; }
                float g1 = GM[lc][tt + NT / 2];
                if (g1 > bg1) { bg1 = g1; bt1 = tt + NT / 2; }
            }
            bg = bg0;
            int bt = bt0;
            if (bg1 > bg0) { bg = bg1; bt = bt1; }
            float4 gb = G4[bt];
            biou = iou_f(px1, py1, px2, py2, pa, gb.x, gb.y, gb.z, gb.w, GA[bt]);
            pdG[thr] = bg;
            pdI[thr] = biou;
        }
        __syncthreads();                       // before GM reuse / W write
    }
    if (lane < NT) W[wave][lane] = bp;
    __syncthreads();                           // W + pdG/pdI + obits complete

    // block winner per t -> gtpart + aux (iou_w, cf, pdg, pdi of winner cell)
    if (thr < NT) {
        unsigned long long pk = W[0][thr];
        if (W[1][thr] > pk) pk = W[1][thr];
        if (W[2][thr] > pk) pk = W[2][thr];
        if (W[3][thr] > pk) pk = W[3][thr];
        int wn = (int)(0xFFFFFFFFu - (unsigned int)(pk & 0xFFFFFFFFu));
        int lc = wn - s * 256;
        float4 p = Bxy[lc];
        float4 g = G4[thr];
        float iw = iou_f(p.x, p.y, p.z, p.w, Bpa[lc], g.x, g.y, g.z, g.w, GA[thr]);
        gtpart[blk * 64 + thr] = pk;
        gtaux [blk * 64 + thr] = make_float4(iw, cfL[lc], pdG[lc], pdI[lc]);
    }

    // --- 8 per-block partials: mask_-free base sums + pg + hm
    bool mk = (biou >= 0.5f);
    bool ob = (obits[thr >> 5] >> (thr & 31)) & 1u;
    float fmk = mk ? 1.f : 0.f, fnmk = 1.f - fmk, fob = ob ? 1.f : 0.f;
    float4 ha = io4[idx], hb = hm4[idx];
    float d0 = ha.x - hb.x, d1 = ha.y - hb.y, d2 = ha.z - hb.z, d3 = ha.w - hb.w;
    float vals[8] = {
        fmk,                          // c2 base  (sum mk)
        (1.f - bg) * fmk,             // sg base
        (1.f - biou) * fmk,           // si base
        cf * fob * fnmk,              // sint base (cf*ob*!mk)
        cf * cf * fnmk,               // spa base  (cf^2*!mk)
        fob * fnmk,                   // sga base  (ob*!mk)
        cf * cf,                      // pg
        d0 * d0 + d1 * d1 + d2 * d2 + d3 * d3   // hm
    };
#pragma unroll
    for (int k = 0; k < 8; ++k) {
        float vv = waveSum(vals[k]);
        if (lane == 0) red[k][wave] = vv;
    }
    __syncthreads();
    if (thr == 0) {
#pragma unroll
        for (int k = 0; k < 8; ++k)
            bpart[blk * 8 + k] = (double)(red[k][0] + red[k][1] + red[k][2] + red[k][3]);
    }
}

// ---------------------------------------------------------------------------
// Kernel D (slim, r10/r13-proven, unchanged): 16 blocks. Label pass; 60x48
// winner scan; dedup'd winner-cell corrections; 48-row partial sum; bacc row
// + fence + ticket; last block finalizes. Producer->consumer coherence via
// the kernel boundary (the only mechanism proven on this chip).
// ---------------------------------------------------------------------------
__global__ __launch_bounds__(256)
void kD(const float* __restrict__ out, const float* __restrict__ labels,
        const unsigned long long* __restrict__ gtpart, const float4* __restrict__ gtaux,
        const double* __restrict__ bpart,
        double* __restrict__ bacc, unsigned int* __restrict__ ticket,
        float* __restrict__ outp) {
    int b = blockIdx.x, thr = threadIdx.x;
    int wave = thr >> 6, lane = thr & 63;

    __shared__ int keys[NT];
    __shared__ unsigned int obits[NPB / 32];   // 384 words (full batch)
    __shared__ int wnL[NT];
    __shared__ float4 auxL[NT];
    __shared__ int finS;
    __shared__ double baccL[256];

    for (int w = thr; w < NPB / 32; w += 256) obits[w] = 0u;
    if (thr < NT) {
        const float* lp = labels + (b * NT + thr) * 5;
        keys[thr] = ((int)(lp[2] * (float)NGRID) << 6) | (int)(lp[1] * (float)NGRID);
    }
    __syncthreads();

    float sxy = 0.f, swh = 0.f, sig_ = 0.f, scnt = 0.f, sgou = 0.f, siou = 0.f;
    if (thr < NT) {
        // label pass
        int key = keys[thr];
        int occ = 0;
        for (int i = 0; i < thr; ++i)
            if (keys[i] == key) occ++;
        const float* lp = labels + (b * NT + thr) * 5;
        float bxf = lp[1] * (float)NGRID;
        float byf = lp[2] * (float)NGRID;
        float lw_ = lp[3], lh_ = lp[4];
        int gi = (int)bxf, gj = (int)byf;
        if (occ < NANCH) {
            int cell = (occ << 12) | (gj << 6) | gi;
            atomicOr(&obits[cell >> 5], 1u << (cell & 31));
            int base = ((b * NANCH * 5 + occ * 5) * NGRID + gj) * NGRID + gi;
            float xs = sigm(out[base]);
            float ys = sigm(out[base + NGRID * NGRID]);
            float ws = sigm(out[base + 2 * NGRID * NGRID]);
            float hs = sigm(out[base + 3 * NGRID * NGRID]);
            float cfl = sigm(out[base + 4 * NGRID * NGRID]);
            float tx = bxf - floorf(bxf);
            float ty = byf - floorf(byf);
            float dx = xs - tx, dy = ys - ty;
            sxy = dx * dx + dy * dy;
            float dw = __logf(ws) - __logf(lw_);
            float dh = __logf(hs) - __logf(lh_);
            swh = dw * dw + dh * dh;
            sig_ = cfl;
            scnt = 1.f;
        }
        // winner scan over this batch's 48 block winners for GT thr
        unsigned long long bestp = 0ull;
        int sbest = 0;
        for (int ss = 0; ss < NBPB; ++ss) {
            unsigned long long pk = gtpart[(b * NBPB + ss) * 64 + thr];
            if (pk > bestp) { bestp = pk; sbest = ss; }   // pk unique across ss
        }
        float4 aux = gtaux[(b * NBPB + sbest) * 64 + thr];
        wnL[thr] = (int)(0xFFFFFFFFu - (unsigned int)(bestp & 0xFFFFFFFFu));
        auxL[thr] = aux;
        sgou = 1.f - ford_inv((unsigned int)(bestp >> 32));
        siou = 1.f - aux.x;
    }
    __syncthreads();   // obits + wnL/auxL complete

    // dedup'd winner-cell corrections (first t claims the cell)
    float dc2 = 0.f, dsg = 0.f, dsi = 0.f, dsint = 0.f, dspa = 0.f, dsga = 0.f;
    if (thr < NT) {
        int wn = wnL[thr];
        bool uniq = true;
        for (int tp = 0; tp < thr; ++tp)
            if (wnL[tp] == wn) { uniq = false; break; }
        if (uniq) {
            float4 aux = auxL[thr];            // (iou_w, cf, pdg, pdi)
            bool mk = (aux.w >= 0.5f);
            bool ob = (obits[wn >> 5] >> (wn & 31)) & 1u;
            float fnmk = mk ? 0.f : 1.f;
            float obnmk = (ob ? 1.f : 0.f) * fnmk;
            dc2 = fnmk;
            dsg = (1.f - aux.z) * fnmk;
            dsi = (1.f - aux.w) * fnmk;
            dsint = aux.y * (1.f - obnmk);
            dspa = aux.y * aux.y * (mk ? 1.f : 0.f);
            dsga = 1.f - obnmk;
        }
    }

    // wave-0 reductions + 48-row partial sums
    double labD[6], corD[6], prtD[8];
    if (wave == 0) {
        labD[0] = (double)waveSum(sxy);
        labD[1] = (double)waveSum(swh);
        labD[2] = (double)waveSum(sig_);
        labD[3] = (double)waveSum(scnt);
        labD[4] = (double)waveSum(sgou);
        labD[5] = (double)waveSum(siou);
        corD[0] = (double)waveSum(dc2);
        corD[1] = (double)waveSum(dsg);
        corD[2] = (double)waveSum(dsi);
        corD[3] = (double)waveSum(dsint);
        corD[4] = (double)waveSum(dspa);
        corD[5] = (double)waveSum(dsga);
#pragma unroll
        for (int k = 0; k < 8; ++k) {
            double v = (lane < NBPB) ? bpart[(b * NBPB + lane) * 8 + k] : 0.0;
            prtD[k] = waveSumD(v);
        }
    }
    __syncthreads();

    // bacc row + release fence + ticket
    if (thr == 0) {
        double* row = &bacc[b * 16];
        row[0]  = prtD[0] + corD[0];   // c2
        row[1]  = prtD[1] + corD[1];   // sg
        row[2]  = prtD[2] + corD[2];   // si
        row[3]  = prtD[3] + corD[3];   // sinter
        row[4]  = prtD[4] + corD[4];   // spa
        row[5]  = prtD[5] + corD[5];   // sga
        row[6]  = labD[4];             // sgou
        row[7]  = labD[5];             // siou
        row[8]  = labD[0];             // sxy
        row[9]  = labD[1];             // swh
        row[10] = labD[2];             // ig
        row[11] = labD[3];             // cnt
        row[12] = prtD[6];             // pg
        row[13] = prtD[7];             // hm
        row[14] = 0.0; row[15] = 0.0;
        __threadfence();
        unsigned int old = atomicAdd(ticket, 1u);
        finS = (old == NBATCH - 1) ? 1 : 0;
    }
    __syncthreads();

    // finalize (last-finishing block; block-uniform branch)
    if (finS) {
        int bb = thr >> 4, k = thr & 15;
        baccL[thr] = atomicAdd(&bacc[bb * 16 + k], 0.0);   // coherent RMW read
        __syncthreads();
        if (thr == 0) {
            double cnt = 0, sxyT = 0, swhT = 0, igT = 0, pgT = 0, hmT = 0;
            double sgouT = 0, siouT = 0, gou2 = 0, iou2 = 0, confbT = 0;
            for (int q = 0; q < NBATCH; ++q) {
                const double* r = &baccL[q * 16];
                cnt += r[11]; sxyT += r[8]; swhT += r[9]; igT += r[10];
                pgT += r[12]; hmT += r[13];
                sgouT += r[6]; siouT += r[7];
                gou2 += r[1] / r[0];
                iou2 += r[2] / r[0];
                confbT += 1.0 - (2.0 * r[3] + 1.0) / (r[4] + r[5] + 1.0);
            }
            double lxy = sxyT / cnt;
            double lwh = swhT / cnt;
            double lgou = sgouT / (double)NLBL + gou2 / (double)NBATCH;
            double liou = siouT / (double)NLBL + iou2 / (double)NBATCH;
            double dice = (2.0 * igT + 1.0) / (pgT + cnt + 1.0);
            if (dice != dice) dice = 1.0;
            double lconf = 1.0 - dice + confbT / (double)NBATCH;
            double total = lxy + lwh + lconf + lgou;
            double hmv = hmT / (double)(4 * NCELL);
            outp[0] = (float)lxy;
            outp[1] = (float)lwh;
            outp[2] = (float)lconf;
            outp[3] = (float)liou;
            outp[4] = (float)lgou;
            outp[5] = (float)total;
            outp[6] = (float)hmv;
        }
    }
}

// ---------------------------------------------------------------------------
extern "C" void kernel_launch(void* const* d_in, const int* in_sizes, int n_in,
                              void* d_out, int out_size, void* d_ws, size_t ws_size,
                              hipStream_t stream) {
    const float* out_p  = (const float*)d_in[0];
    const float* labels = (const float*)d_in[1];
    const float4* io4   = (const float4*)d_in[2];
    const float4* hm4   = (const float4*)d_in[3];
    float* o = (float*)d_out;

    char* ws = (char*)d_ws;
    unsigned long long* gtpart = (unsigned long long*)(ws);            // 393216 B
    float4* gtaux = (float4*)(ws + 393216);                            // 786432 B
    double* bpart = (double*)(ws + 1179648);                           //  49152 B
    double* bacc  = (double*)(ws + 1228800);                           //   2048 B
    unsigned int* ticket = (unsigned int*)(ws + 1230848);              //     64 B
    // ~1.23 MB total; all consumed data fully written each call (kB zeroes
    // the ticket) — no memset, no zero-init ordering hazards. Producer ->
    // consumer crosses the kernel boundary (the only coherence mechanism
    // proven on this chip: r11/r12 intra-dispatch attempts both failed).

    hipLaunchKernelGGL(kB, dim3(NBLKB), dim3(256), 0, stream, out_p, labels, io4, hm4,
                       gtpart, gtaux, bpart, ticket);
    hipLaunchKernelGGL(kD, dim3(NBATCH), dim3(256), 0, stream, out_p, labels,
                       gtpart, gtaux, bpart, bacc, ticket, o);
}